// Round 9
// baseline (2107.818 us; speedup 1.0000x reference)
//
#include <hip/hip_runtime.h>

#define QS 8
#define KC 1024
#define DD 256
#define TT 8192
#define NN 65536
#define TAU 0.04f
#define FLAGCAP 49152

typedef short bf16x8 __attribute__((ext_vector_type(8)));
typedef short s16x4 __attribute__((ext_vector_type(4)));
typedef float f32x4 __attribute__((ext_vector_type(4)));

__device__ __forceinline__ unsigned short f2bf(float f) {
    union { float f; unsigned u; } c; c.f = f;
    const unsigned r = c.u + 0x7FFFu + ((c.u >> 16) & 1u);
    return (unsigned short)(r >> 16);
}
__device__ __forceinline__ float bf2f(unsigned short h) {
    union { unsigned u; float f; } c; c.u = ((unsigned)h) << 16;
    return c.f;
}

// ---------------------------------------------------------------------------
// Encoder: z = conv1d(x) -> res (token-major [N][256]); zero loss + flag cnts.
// ---------------------------------------------------------------------------
__global__ __launch_bounds__(256) void encode_init_kernel(
    const float* __restrict__ x, const float* __restrict__ ew,
    const float* __restrict__ eb, float* __restrict__ res,
    float* __restrict__ lossAcc, int* __restrict__ flagCnt)
{
    if (blockIdx.x == 0 && threadIdx.x == 0) *lossAcc = 0.0f;
    if (blockIdx.x == 0 && threadIdx.x < QS) flagCnt[threadIdx.x] = 0;
    const int d = threadIdx.x;                 // 256 == DD
    const float w0 = ew[d*3 + 0];
    const float w1 = ew[d*3 + 1];
    const float w2 = ew[d*3 + 2];
    const float b  = eb[d];
    #pragma unroll 4
    for (int tt = 0; tt < 16; ++tt) {
        const long n = (long)blockIdx.x * 16 + tt;   // grid = 4096
        const int t = (int)(n & (TT - 1));
        const float xm = (t > 0)      ? x[n - 1] : 0.0f;
        const float x0 = x[n];
        const float xp = (t < TT - 1) ? x[n + 1] : 0.0f;
        res[n * DD + d] = b + w0*xm + w1*x0 + w2*xp;
    }
}

// ---------------------------------------------------------------------------
// c2[s][k] = ||codebook[s][k]||^2 ; one wave per code.
// ---------------------------------------------------------------------------
__global__ __launch_bounds__(256) void c2_kernel(
    const float* __restrict__ cbs, float* __restrict__ c2)
{
    const int w = (int)((blockIdx.x * blockDim.x + threadIdx.x) >> 6);
    const int lane = threadIdx.x & 63;
    if (w >= QS * KC) return;
    const float* row = cbs + (long)w * DD;
    float s = 0.0f;
    #pragma unroll
    for (int q = 0; q < DD / 64; ++q) {
        const float v = row[lane + 64*q];
        s += v * v;
    }
    #pragma unroll
    for (int off = 32; off; off >>= 1) s += __shfl_down(s, off, 64);
    if (lane == 0) c2[w] = s;
}

// ---------------------------------------------------------------------------
// Per-stage codebook hi/lo bf16 split: cbbf[0][KC][DD]=hi, cbbf[1][KC][DD]=lo.
// ---------------------------------------------------------------------------
__global__ __launch_bounds__(256) void cb_prep_stage_kernel(
    const float* __restrict__ cb, short* __restrict__ cbbf)
{
    const int i = (blockIdx.x * 256 + threadIdx.x) * 4;   // grid = KC*DD/1024
    const float4 v = *reinterpret_cast<const float4*>(&cb[i]);
    const float fv[4] = {v.x, v.y, v.z, v.w};
    s16x4 hv, lv;
    #pragma unroll
    for (int e = 0; e < 4; ++e) {
        const unsigned short hh = f2bf(fv[e]);
        hv[e] = (short)hh;
        lv[e] = (short)f2bf(fv[e] - bf2f(hh));
    }
    *reinterpret_cast<s16x4*>(&cbbf[i])           = hv;
    *reinterpret_cast<s16x4*>(&cbbf[KC*DD + i])   = lv;
}

// ---------------------------------------------------------------------------
// Fused RVQ stage, bf16 MFMA — OCCUPANCY version.
// 64-token blocks (grid 1024 -> 4 blocks/CU, 16 waves/CU, 4 waves/SIMD).
// Each wave owns 16 tokens; A-frags ah/al[8] (64 VGPR).
// LDS: round-7 proven 32 KB double-buffer, chunk-slot conflict-free layout.
// Round = 64 codes x 64 k; register prefetch 1-deep (T14).
// ---------------------------------------------------------------------------
__global__ __launch_bounds__(256, 4) void rvq_pass1_kernel(
    const float* __restrict__ cb,    // [KC][DD] fp32 (epilogue gather)
    const short* __restrict__ cbbf,  // [2][KC][DD] bf16 (this stage)
    const float* __restrict__ c2,    // [KC]
    float* __restrict__ res,         // [NN][DD]
    float* __restrict__ lossAcc,
    int* __restrict__ flagCnt,       // this stage
    int* __restrict__ flagList)      // shared list, cap FLAGCAP
{
    __shared__ __align__(16) short Bt[2][8192];   // [buf][plane*4096+slot*8] = 32 KB
    __shared__ int idxArr[64];

    const int tid = threadIdx.x;
    const int w   = tid >> 6;
    const int l   = tid & 63;
    const int l15 = l & 15;
    const int l4  = l >> 4;
    const long n0 = (long)blockIdx.x * 64;

    // ---- orientation probe (exact arithmetic; proven round 5) ----
    int tr;
    {
        bf16x8 pa, pb;
        const short av = (short)f2bf((float)l15);
        const short bv = (short)f2bf(0.03125f);
        #pragma unroll
        for (int e = 0; e < 8; ++e) { pa[e] = av; pb[e] = bv; }
        f32x4 pacc = (f32x4){0.f, 0.f, 0.f, 0.f};
        pacc = __builtin_amdgcn_mfma_f32_16x16x32_bf16(pa, pb, pacc, 0, 0, 0);
        const float p1 = __shfl(pacc[1], 0, 64);
        tr = (p1 < 0.5f) ? 1 : 0;
    }

    // ---- A fragments: token = n0 + w*16 + l15, k-run (l>>4)*8 ----
    bf16x8 ah[8], al[8];
    #pragma unroll
    for (int kc = 0; kc < 8; ++kc) {
        const long n = n0 + w*16 + l15;
        const float* p = &res[n*DD + kc*32 + l4*8];
        const float4 v0 = *reinterpret_cast<const float4*>(p);
        const float4 v1 = *reinterpret_cast<const float4*>(p + 4);
        const float xv[8] = {v0.x, v0.y, v0.z, v0.w, v1.x, v1.y, v1.z, v1.w};
        bf16x8 hv, lv;
        #pragma unroll
        for (int e = 0; e < 8; ++e) {
            const unsigned short hh = f2bf(xv[e]);
            hv[e] = (short)hh;
            lv[e] = (short)f2bf(xv[e] - bf2f(hh));
        }
        ah[kc] = hv; al[kc] = lv;
    }

    float b1[4], b2[4]; int i1[4];
    #pragma unroll
    for (int r = 0; r < 4; ++r) { b1[r] = 1e30f; b2[r] = 1e30f; i1[r] = 0; }

    // staging: thread owns p0 = tid, p1 = tid+256 (p = kchunk*64 + code)
    const int p0 = tid, p1 = tid + 256;
    bf16x8 ph0, pl0, ph1, pl1;

    auto loadPairs = [&](int t) {
        const int cg = t >> 2, kp = t & 3;
        const long o0 = (long)(cg*64 + (p0 & 63))*DD + kp*64 + (p0 >> 6)*8;
        const long o1 = (long)(cg*64 + (p1 & 63))*DD + kp*64 + (p1 >> 6)*8;
        ph0 = *reinterpret_cast<const bf16x8*>(cbbf + o0);
        pl0 = *reinterpret_cast<const bf16x8*>(cbbf + KC*DD + o0);
        ph1 = *reinterpret_cast<const bf16x8*>(cbbf + o1);
        pl1 = *reinterpret_cast<const bf16x8*>(cbbf + KC*DD + o1);
    };
    auto writePairs = [&](int buf) {
        *reinterpret_cast<bf16x8*>(&Bt[buf][p0*8])        = ph0;
        *reinterpret_cast<bf16x8*>(&Bt[buf][4096 + p0*8]) = pl0;
        *reinterpret_cast<bf16x8*>(&Bt[buf][p1*8])        = ph1;
        *reinterpret_cast<bf16x8*>(&Bt[buf][4096 + p1*8]) = pl1;
    };

    loadPairs(0);
    writePairs(0);
    __syncthreads();

    for (int cg = 0; cg < 16; ++cg) {
      f32x4 acc[4];
      #pragma unroll
      for (int nt = 0; nt < 4; ++nt) acc[nt] = (f32x4){0.f, 0.f, 0.f, 0.f};

      for (int kp = 0; kp < 4; ++kp) {
        const int t = cg*4 + kp, buf = t & 1;
        if (t < 63) loadPairs(t + 1);      // prefetch: latency hides under MFMA

        #pragma unroll
        for (int kc2 = 0; kc2 < 2; ++kc2) {
          const int kc = kp*2 + kc2;
          #pragma unroll
          for (int nt = 0; nt < 4; ++nt) {
            const int slot = ((kc2*4 + l4)*64 + nt*16 + l15)*8;
            const bf16x8 bh = *reinterpret_cast<const bf16x8*>(&Bt[buf][slot]);
            const bf16x8 bl = *reinterpret_cast<const bf16x8*>(&Bt[buf][4096 + slot]);
            acc[nt] = __builtin_amdgcn_mfma_f32_16x16x32_bf16(ah[kc], bh, acc[nt], 0, 0, 0);
            acc[nt] = __builtin_amdgcn_mfma_f32_16x16x32_bf16(al[kc], bh, acc[nt], 0, 0, 0);
            acc[nt] = __builtin_amdgcn_mfma_f32_16x16x32_bf16(ah[kc], bl, acc[nt], 0, 0, 0);
          }
        }

        if (t < 63) writePairs(buf ^ 1);   // conflict-free ds_write_b128 x4
        __syncthreads();
      }

      if (tr == 0) {
        // token on reg side (row=l4*4+j), code on lane side (col=l15)
        #pragma unroll
        for (int nt = 0; nt < 4; ++nt) {
          const int code = cg*64 + nt*16 + l15;
          const float cc = c2[code];
          #pragma unroll
          for (int j = 0; j < 4; ++j) {
            const float dist = cc - 2.0f*acc[nt][j];
            if (dist < b1[j])      { b2[j] = b1[j]; b1[j] = dist; i1[j] = code; }
            else if (dist < b2[j]) { b2[j] = dist; }
          }
        }
      } else {
        // token on lane side (l15), code on reg side (l4*4+j)
        #pragma unroll
        for (int nt = 0; nt < 4; ++nt) {
          #pragma unroll
          for (int j = 0; j < 4; ++j) {
            const int code = cg*64 + nt*16 + l4*4 + j;
            const float cc = c2[code];
            const float dist = cc - 2.0f*acc[nt][j];
            if (dist < b1[0])      { b2[0] = b1[0]; b1[0] = dist; i1[0] = code; }
            else if (dist < b2[0]) { b2[0] = dist; }
          }
        }
      }
    }

    if (tr == 0) {
      // reduce over the 16 code-lanes (l&15): masks 1,2,4,8
      #pragma unroll
      for (int m = 1; m < 16; m <<= 1) {
        #pragma unroll
        for (int r = 0; r < 4; ++r) {
          const float ob1 = __shfl_xor(b1[r], m, 64);
          const float ob2 = __shfl_xor(b2[r], m, 64);
          const int   oi1 = __shfl_xor(i1[r], m, 64);
          const float nb2 = fminf(fminf(b2[r], ob2), fmaxf(b1[r], ob1));
          if (ob1 < b1[r] || (ob1 == b1[r] && oi1 < i1[r])) { b1[r] = ob1; i1[r] = oi1; }
          b2[r] = nb2;
        }
      }
      if (l15 == 0) {
        #pragma unroll
        for (int j = 0; j < 4; ++j) {
          const int row = w*16 + l4*4 + j;
          idxArr[row] = i1[j];
          if (b2[j] - b1[j] < TAU) {
            const int pos = atomicAdd(flagCnt, 1);
            if (pos < FLAGCAP)
              flagList[pos] = (int)(((n0 + row) << 10) | (unsigned)i1[j]);
          }
        }
      }
    } else {
      // reduce over the 4 l4-lanes (same l15): masks 16,32
      #pragma unroll
      for (int m = 16; m <= 32; m <<= 1) {
        const float ob1 = __shfl_xor(b1[0], m, 64);
        const float ob2 = __shfl_xor(b2[0], m, 64);
        const int   oi1 = __shfl_xor(i1[0], m, 64);
        const float nb2 = fminf(fminf(b2[0], ob2), fmaxf(b1[0], ob1));
        if (ob1 < b1[0] || (ob1 == b1[0] && oi1 < i1[0])) { b1[0] = ob1; i1[0] = oi1; }
        b2[0] = nb2;
      }
      if (l4 == 0) {
        const int row = w*16 + l15;
        idxArr[row] = i1[0];
        if (b2[0] - b1[0] < TAU) {
          const int pos = atomicAdd(flagCnt, 1);
          if (pos < FLAGCAP)
            flagList[pos] = (int)(((n0 + row) << 10) | (unsigned)i1[0]);
        }
      }
    }
    __syncthreads();

    // residual update in place + commitment-loss partial (float4 vectorized:
    // 4 rows/iter, thread t -> row it*4+(t>>6), cols (t&63)*4..+3)
    float lsum = 0.0f;
    const int rw = tid >> 6;        // row-within-quad
    const int cc4 = (tid & 63) * 4; // column base
    #pragma unroll 4
    for (int it = 0; it < 16; ++it) {
        const int r = it*4 + rw;
        const long n = n0 + r;
        const int ix = idxArr[r];
        float4 rv = *reinterpret_cast<const float4*>(&res[n*DD + cc4]);
        const float4 cv = *reinterpret_cast<const float4*>(&cb[(long)ix*DD + cc4]);
        rv.x -= cv.x; rv.y -= cv.y; rv.z -= cv.z; rv.w -= cv.w;
        *reinterpret_cast<float4*>(&res[n*DD + cc4]) = rv;
        lsum += rv.x*rv.x + rv.y*rv.y + rv.z*rv.z + rv.w*rv.w;
    }
    #pragma unroll
    for (int off = 32; off; off >>= 1) lsum += __shfl_down(lsum, off, 64);
    if (l == 0) atomicAdd(lossAcc, lsum);
}

// ---------------------------------------------------------------------------
// Exact fp32 recheck for margin-flagged tokens. Fixed grid, grid-strided.
// ---------------------------------------------------------------------------
__global__ __launch_bounds__(256) void recheck_kernel(
    const float* __restrict__ cb, const float* __restrict__ c2,
    float* __restrict__ res, float* __restrict__ lossAcc,
    const int* __restrict__ flagCnt, const int* __restrict__ flagList)
{
    __shared__ float rorig[DD];
    __shared__ float sD[256];
    __shared__ int   sI[256];
    const int cnt = min(*flagCnt, FLAGCAP);
    const int tid = threadIdx.x;
    for (int f = blockIdx.x; f < cnt; f += gridDim.x) {
        const int packed = flagList[f];
        const long n  = packed >> 10;
        const int old = packed & 1023;
        __syncthreads();   // protect LDS reuse across f-iterations
        const float rme = res[n*DD + tid] + cb[(long)old*DD + tid];
        rorig[tid] = rme;
        __syncthreads();
        float bd = 1e30f; int bi = 0;
        #pragma unroll
        for (int q = 0; q < 4; ++q) {
            const int code = tid + 256*q;
            const float* crow = &cb[(long)code*DD];
            float dot = 0.f;
            for (int d = 0; d < DD; ++d) dot += rorig[d]*crow[d];
            const float dist = c2[code] - 2.0f*dot;
            if (dist < bd || (dist == bd && code < bi)) { bd = dist; bi = code; }
        }
        sD[tid] = bd; sI[tid] = bi;
        __syncthreads();
        for (int s = 128; s; s >>= 1) {
            if (tid < s) {
                const float d2 = sD[tid + s]; const int i2 = sI[tid + s];
                if (d2 < sD[tid] || (d2 == sD[tid] && i2 < sI[tid])) { sD[tid] = d2; sI[tid] = i2; }
            }
            __syncthreads();
        }
        const int best = sI[0];
        if (best != old) {
            const float rn = rorig[tid] - cb[(long)best*DD + tid];
            const float ro = res[n*DD + tid];
            res[n*DD + tid] = rn;
            float delta = rn*rn - ro*ro;
            #pragma unroll
            for (int off = 32; off; off >>= 1) delta += __shfl_down(delta, off, 64);
            if ((tid & 63) == 0) atomicAdd(lossAcc, delta);
        }
    }
}

// ---------------------------------------------------------------------------
// Decoder: quant = z - res_final (z recomputed); conv1d to 1 channel + loss out.
// ---------------------------------------------------------------------------
__global__ __launch_bounds__(256) void decode_kernel(
    const float* __restrict__ x,  const float* __restrict__ ew,
    const float* __restrict__ eb, const float* __restrict__ res,
    const float* __restrict__ dw, const float* __restrict__ db,
    const float* __restrict__ lossAcc, float* __restrict__ out)
{
    const long n = (long)blockIdx.x * 4 + (threadIdx.x >> 6);
    const int lane = threadIdx.x & 63;
    const int t = (int)(n & (TT - 1));
    float sum = 0.0f;
    #pragma unroll
    for (int k = 0; k < 3; ++k) {
        const int tm = t + k - 1;
        if (tm < 0 || tm > TT - 1) continue;
        const long m = n + k - 1;
        const float xm = (tm > 0)      ? x[m - 1] : 0.0f;
        const float x0 = x[m];
        const float xp = (tm < TT - 1) ? x[m + 1] : 0.0f;
        #pragma unroll
        for (int q = 0; q < 4; ++q) {
            const int d = lane + 64 * q;
            const float z = eb[d] + ew[d*3]*xm + ew[d*3 + 1]*x0 + ew[d*3 + 2]*xp;
            const float quant = z - res[m * DD + d];
            sum += quant * dw[d*3 + k];
        }
    }
    #pragma unroll
    for (int off = 32; off; off >>= 1) sum += __shfl_down(sum, off, 64);
    if (lane == 0) out[n] = sum + db[0];
    if (blockIdx.x == 0 && threadIdx.x == 0)
        out[NN] = lossAcc[0] * (1.0f / ((float)NN * (float)DD));
}

// ---------------------------------------------------------------------------
// Workspace: d_ws = res 64MB + lossAcc(16B) + per-stage cbbf 1MB  (~65MB).
// d_out scratch until decode: [0..7]=flagCnt[8], [8..8199]=c2, [8200..]=flagList.
// ---------------------------------------------------------------------------
extern "C" void kernel_launch(void* const* d_in, const int* in_sizes, int n_in,
                              void* d_out, int out_size, void* d_ws, size_t ws_size,
                              hipStream_t stream)
{
    const float* x     = (const float*)d_in[0];
    const float* enc_w = (const float*)d_in[1];
    const float* enc_b = (const float*)d_in[2];
    const float* dec_w = (const float*)d_in[3];
    const float* dec_b = (const float*)d_in[4];
    const float* cbs   = (const float*)d_in[5];
    float* out = (float*)d_out;

    float* res      = (float*)d_ws;                 // [NN][DD] = 64 MB
    float* lossAcc  = res + (size_t)NN * DD;        // 1 float (+pad)
    short* cbbf     = (short*)(lossAcc + 4);        // [2][KC][DD] bf16 = 1 MB
    int*   flagCnt  = (int*)out;                    // [QS] in d_out
    float* c2       = out + 8;                      // [QS*KC] in d_out
    int*   flagList = (int*)(out + 8 + QS * KC);    // cap FLAGCAP in d_out

    hipLaunchKernelGGL(encode_init_kernel, dim3(NN / 16), dim3(256), 0, stream,
                       x, enc_w, enc_b, res, lossAcc, flagCnt);
    hipLaunchKernelGGL(c2_kernel, dim3(QS * KC / 4), dim3(256), 0, stream,
                       cbs, c2);
    for (int s = 0; s < QS; ++s) {
        hipLaunchKernelGGL(cb_prep_stage_kernel, dim3(KC * DD / 1024), dim3(256), 0, stream,
                           cbs + (size_t)s * KC * DD, cbbf);
        hipLaunchKernelGGL(rvq_pass1_kernel, dim3(NN / 64), dim3(256), 0, stream,
                           cbs + (size_t)s * KC * DD, cbbf,
                           c2 + (size_t)s * KC,
                           res, lossAcc, flagCnt + s, flagList);
        hipLaunchKernelGGL(recheck_kernel, dim3(256), dim3(256), 0, stream,
                           cbs + (size_t)s * KC * DD,
                           c2 + (size_t)s * KC,
                           res, lossAcc, flagCnt + s, flagList);
    }
    hipLaunchKernelGGL(decode_kernel, dim3(NN / 4), dim3(256), 0, stream,
                       x, enc_w, enc_b, res, dec_w, dec_b, lossAcc, out);
}

// Round 10
// 1630.768 us; speedup vs baseline: 1.2925x; 1.2925x over previous
//
#include <hip/hip_runtime.h>

#define QS 8
#define KC 1024
#define DD 256
#define TT 8192
#define NN 65536
#define TAU 0.06f
#define FLAGCAP 49152

typedef _Float16 half8 __attribute__((ext_vector_type(8)));
typedef _Float16 half4 __attribute__((ext_vector_type(4)));
typedef float f32x4 __attribute__((ext_vector_type(4)));

__device__ __forceinline__ unsigned short f2bf(float f) {
    union { float f; unsigned u; } c; c.f = f;
    const unsigned r = c.u + 0x7FFFu + ((c.u >> 16) & 1u);
    return (unsigned short)(r >> 16);
}

// ---------------------------------------------------------------------------
// Encoder: z = conv1d(x) -> res (token-major [N][256]); zero loss + flag cnts.
// ---------------------------------------------------------------------------
__global__ __launch_bounds__(256) void encode_init_kernel(
    const float* __restrict__ x, const float* __restrict__ ew,
    const float* __restrict__ eb, float* __restrict__ res,
    float* __restrict__ lossAcc, int* __restrict__ flagCnt)
{
    if (blockIdx.x == 0 && threadIdx.x == 0) *lossAcc = 0.0f;
    if (blockIdx.x == 0 && threadIdx.x < QS) flagCnt[threadIdx.x] = 0;
    const int d = threadIdx.x;                 // 256 == DD
    const float w0 = ew[d*3 + 0];
    const float w1 = ew[d*3 + 1];
    const float w2 = ew[d*3 + 2];
    const float b  = eb[d];
    #pragma unroll 4
    for (int tt = 0; tt < 16; ++tt) {
        const long n = (long)blockIdx.x * 16 + tt;   // grid = 4096
        const int t = (int)(n & (TT - 1));
        const float xm = (t > 0)      ? x[n - 1] : 0.0f;
        const float x0 = x[n];
        const float xp = (t < TT - 1) ? x[n + 1] : 0.0f;
        res[n * DD + d] = b + w0*xm + w1*x0 + w2*xp;
    }
}

// ---------------------------------------------------------------------------
// c2[s][k] = ||codebook[s][k]||^2 ; one wave per code.
// ---------------------------------------------------------------------------
__global__ __launch_bounds__(256) void c2_kernel(
    const float* __restrict__ cbs, float* __restrict__ c2)
{
    const int w = (int)((blockIdx.x * blockDim.x + threadIdx.x) >> 6);
    const int lane = threadIdx.x & 63;
    if (w >= QS * KC) return;
    const float* row = cbs + (long)w * DD;
    float s = 0.0f;
    #pragma unroll
    for (int q = 0; q < DD / 64; ++q) {
        const float v = row[lane + 64*q];
        s += v * v;
    }
    #pragma unroll
    for (int off = 32; off; off >>= 1) s += __shfl_down(s, off, 64);
    if (lane == 0) c2[w] = s;
}

// ---------------------------------------------------------------------------
// Per-stage codebook f16 hi plane only: cbh[KC][DD] (512 KB).
// The dropped r·Bl term is ~6e-3 in distance — covered by TAU + exact recheck.
// ---------------------------------------------------------------------------
__global__ __launch_bounds__(256) void cb_prep_stage_kernel(
    const float* __restrict__ cb, _Float16* __restrict__ cbh)
{
    const int i = (blockIdx.x * 256 + threadIdx.x) * 4;   // grid = KC*DD/1024
    const float4 v = *reinterpret_cast<const float4*>(&cb[i]);
    half4 hv;
    hv[0] = (_Float16)v.x; hv[1] = (_Float16)v.y;
    hv[2] = (_Float16)v.z; hv[3] = (_Float16)v.w;
    *reinterpret_cast<half4*>(&cbh[i]) = hv;
}

// ---------------------------------------------------------------------------
// Fused RVQ stage, f16 MFMA 2-term (Ah*Bh + Al*Bh), round-7 chassis.
// 128-token blocks, round = 64 codes x 64 k, LDS hi-plane only:
// Bt[2][64*64] f16 = 16 KB double-buffered, chunk-slot conflict-free layout.
// Register prefetch 1-deep (T14). dist = c2 - 2*dot; best/2nd-best + recheck.
// ---------------------------------------------------------------------------
__global__ __launch_bounds__(256, 2) void rvq_pass1_kernel(
    const float* __restrict__ cb,      // [KC][DD] fp32 (epilogue gather)
    const _Float16* __restrict__ cbh,  // [KC][DD] f16 (this stage)
    const float* __restrict__ c2,      // [KC]
    float* __restrict__ res,           // [NN][DD]
    float* __restrict__ lossAcc,
    int* __restrict__ flagCnt,         // this stage
    int* __restrict__ flagList)        // shared list, cap FLAGCAP
{
    __shared__ __align__(16) _Float16 Bt[2][4096];  // [buf][(kchunk*64+code)*8] = 16 KB
    __shared__ int idxArr[128];

    const int tid = threadIdx.x;
    const int w   = tid >> 6;
    const int l   = tid & 63;
    const int l15 = l & 15;
    const int l4  = l >> 4;
    const long n0 = (long)blockIdx.x * 128;

    // ---- orientation probe (exact arithmetic in f16; ints<16 & 1/32 exact) --
    int tr;
    {
        half8 pa, pb;
        #pragma unroll
        for (int e = 0; e < 8; ++e) {
            pa[e] = (_Float16)l15;
            pb[e] = (_Float16)0.03125f;
        }
        f32x4 pacc = (f32x4){0.f, 0.f, 0.f, 0.f};
        pacc = __builtin_amdgcn_mfma_f32_16x16x32_f16(pa, pb, pacc, 0, 0, 0);
        const float p1 = __shfl(pacc[1], 0, 64);
        tr = (p1 < 0.5f) ? 1 : 0;
    }

    // ---- A fragments: token = n0 + w*32 + mt*16 + l15, k-run (l>>4)*8 ----
    // f16 hi/lo split of fp32 residual (hi+lo captures ~22 mantissa bits).
    half8 ah[2][8], al[2][8];
    #pragma unroll
    for (int mt = 0; mt < 2; ++mt) {
      #pragma unroll
      for (int kc = 0; kc < 8; ++kc) {
        const long n = n0 + w*32 + mt*16 + l15;
        const float* p = &res[n*DD + kc*32 + l4*8];
        const float4 v0 = *reinterpret_cast<const float4*>(p);
        const float4 v1 = *reinterpret_cast<const float4*>(p + 4);
        const float xv[8] = {v0.x, v0.y, v0.z, v0.w, v1.x, v1.y, v1.z, v1.w};
        half8 hv, lv;
        #pragma unroll
        for (int e = 0; e < 8; ++e) {
            const _Float16 hh = (_Float16)xv[e];
            hv[e] = hh;
            lv[e] = (_Float16)(xv[e] - (float)hh);
        }
        ah[mt][kc] = hv; al[mt][kc] = lv;
      }
    }

    float b1[8], b2[8]; int i1[8];
    #pragma unroll
    for (int r = 0; r < 8; ++r) { b1[r] = 1e30f; b2[r] = 1e30f; i1[r] = 0; }

    // staging: thread owns p0 = tid, p1 = tid+256 (p = kchunk*64 + code)
    const int p0 = tid, p1 = tid + 256;
    half8 ph0, ph1;

    auto loadPairs = [&](int t) {
        const int cg = t >> 2, kp = t & 3;
        const long o0 = (long)(cg*64 + (p0 & 63))*DD + kp*64 + (p0 >> 6)*8;
        const long o1 = (long)(cg*64 + (p1 & 63))*DD + kp*64 + (p1 >> 6)*8;
        ph0 = *reinterpret_cast<const half8*>(cbh + o0);
        ph1 = *reinterpret_cast<const half8*>(cbh + o1);
    };
    auto writePairs = [&](int buf) {
        *reinterpret_cast<half8*>(&Bt[buf][p0*8]) = ph0;
        *reinterpret_cast<half8*>(&Bt[buf][p1*8]) = ph1;
    };

    loadPairs(0);
    writePairs(0);
    __syncthreads();

    for (int cg = 0; cg < 16; ++cg) {
      f32x4 acc[2][4];
      #pragma unroll
      for (int mt = 0; mt < 2; ++mt)
        #pragma unroll
        for (int nt = 0; nt < 4; ++nt)
          acc[mt][nt] = (f32x4){0.f, 0.f, 0.f, 0.f};

      for (int kp = 0; kp < 4; ++kp) {
        const int t = cg*4 + kp, buf = t & 1;
        if (t < 63) loadPairs(t + 1);      // prefetch: latency hides under MFMA

        #pragma unroll
        for (int kc2 = 0; kc2 < 2; ++kc2) {
          const int kc = kp*2 + kc2;
          #pragma unroll
          for (int nt = 0; nt < 4; ++nt) {
            const int slot = ((kc2*4 + l4)*64 + nt*16 + l15)*8;
            const half8 bh = *reinterpret_cast<const half8*>(&Bt[buf][slot]);
            #pragma unroll
            for (int mt = 0; mt < 2; ++mt) {
              acc[mt][nt] = __builtin_amdgcn_mfma_f32_16x16x32_f16(ah[mt][kc], bh, acc[mt][nt], 0, 0, 0);
              acc[mt][nt] = __builtin_amdgcn_mfma_f32_16x16x32_f16(al[mt][kc], bh, acc[mt][nt], 0, 0, 0);
            }
          }
        }

        if (t < 63) writePairs(buf ^ 1);   // conflict-free ds_write_b128 x2
        __syncthreads();
      }

      if (tr == 0) {
        // token on reg side (row=l4*4+j), code on lane side (col=l15)
        #pragma unroll
        for (int nt = 0; nt < 4; ++nt) {
          const int code = cg*64 + nt*16 + l15;
          const float cc = c2[code];
          #pragma unroll
          for (int mt = 0; mt < 2; ++mt) {
            #pragma unroll
            for (int j = 0; j < 4; ++j) {
              const float dist = cc - 2.0f*acc[mt][nt][j];
              const int r = mt*4 + j;
              if (dist < b1[r])      { b2[r] = b1[r]; b1[r] = dist; i1[r] = code; }
              else if (dist < b2[r]) { b2[r] = dist; }
            }
          }
        }
      } else {
        // token on lane side (l15), code on reg side (l4*4+j)
        #pragma unroll
        for (int nt = 0; nt < 4; ++nt) {
          #pragma unroll
          for (int j = 0; j < 4; ++j) {
            const int code = cg*64 + nt*16 + l4*4 + j;
            const float cc = c2[code];
            #pragma unroll
            for (int mt = 0; mt < 2; ++mt) {
              const float dist = cc - 2.0f*acc[mt][nt][j];
              if (dist < b1[mt])      { b2[mt] = b1[mt]; b1[mt] = dist; i1[mt] = code; }
              else if (dist < b2[mt]) { b2[mt] = dist; }
            }
          }
        }
      }
    }

    if (tr == 0) {
      #pragma unroll
      for (int m = 1; m < 16; m <<= 1) {
        #pragma unroll
        for (int r = 0; r < 8; ++r) {
          const float ob1 = __shfl_xor(b1[r], m, 64);
          const float ob2 = __shfl_xor(b2[r], m, 64);
          const int   oi1 = __shfl_xor(i1[r], m, 64);
          const float nb2 = fminf(fminf(b2[r], ob2), fmaxf(b1[r], ob1));
          if (ob1 < b1[r] || (ob1 == b1[r] && oi1 < i1[r])) { b1[r] = ob1; i1[r] = oi1; }
          b2[r] = nb2;
        }
      }
      if (l15 == 0) {
        #pragma unroll
        for (int mt = 0; mt < 2; ++mt)
          #pragma unroll
          for (int j = 0; j < 4; ++j) {
            const int r = mt*4 + j;
            const int row = w*32 + mt*16 + l4*4 + j;
            idxArr[row] = i1[r];
            if (b2[r] - b1[r] < TAU) {
              const int pos = atomicAdd(flagCnt, 1);
              if (pos < FLAGCAP)
                flagList[pos] = (int)(((n0 + row) << 10) | (unsigned)i1[r]);
            }
          }
      }
    } else {
      #pragma unroll
      for (int m = 16; m <= 32; m <<= 1) {
        #pragma unroll
        for (int r = 0; r < 2; ++r) {
          const float ob1 = __shfl_xor(b1[r], m, 64);
          const float ob2 = __shfl_xor(b2[r], m, 64);
          const int   oi1 = __shfl_xor(i1[r], m, 64);
          const float nb2 = fminf(fminf(b2[r], ob2), fmaxf(b1[r], ob1));
          if (ob1 < b1[r] || (ob1 == b1[r] && oi1 < i1[r])) { b1[r] = ob1; i1[r] = oi1; }
          b2[r] = nb2;
        }
      }
      if (l4 == 0) {
        #pragma unroll
        for (int mt = 0; mt < 2; ++mt) {
          const int row = w*32 + mt*16 + l15;
          idxArr[row] = i1[mt];
          if (b2[mt] - b1[mt] < TAU) {
            const int pos = atomicAdd(flagCnt, 1);
            if (pos < FLAGCAP)
              flagList[pos] = (int)(((n0 + row) << 10) | (unsigned)i1[mt]);
          }
        }
      }
    }
    __syncthreads();

    // residual update in place + commitment-loss partial (float4 vectorized:
    // 4 rows/iter, thread t -> row it*4+(t>>6), cols (t&63)*4..+3)
    float lsum = 0.0f;
    const int rw = tid >> 6;        // row-within-quad
    const int cc4 = (tid & 63) * 4; // column base
    #pragma unroll 4
    for (int it = 0; it < 32; ++it) {
        const int r = it*4 + rw;
        const long n = n0 + r;
        const int ix = idxArr[r];
        float4 rv = *reinterpret_cast<const float4*>(&res[n*DD + cc4]);
        const float4 cv = *reinterpret_cast<const float4*>(&cb[(long)ix*DD + cc4]);
        rv.x -= cv.x; rv.y -= cv.y; rv.z -= cv.z; rv.w -= cv.w;
        *reinterpret_cast<float4*>(&res[n*DD + cc4]) = rv;
        lsum += rv.x*rv.x + rv.y*rv.y + rv.z*rv.z + rv.w*rv.w;
    }
    #pragma unroll
    for (int off = 32; off; off >>= 1) lsum += __shfl_down(lsum, off, 64);
    if (l == 0) atomicAdd(lossAcc, lsum);
}

// ---------------------------------------------------------------------------
// Exact fp32 recheck for margin-flagged tokens. Fixed grid, grid-strided.
// ---------------------------------------------------------------------------
__global__ __launch_bounds__(256) void recheck_kernel(
    const float* __restrict__ cb, const float* __restrict__ c2,
    float* __restrict__ res, float* __restrict__ lossAcc,
    const int* __restrict__ flagCnt, const int* __restrict__ flagList)
{
    __shared__ float rorig[DD];
    __shared__ float sD[256];
    __shared__ int   sI[256];
    const int cnt = min(*flagCnt, FLAGCAP);
    const int tid = threadIdx.x;
    for (int f = blockIdx.x; f < cnt; f += gridDim.x) {
        const int packed = flagList[f];
        const long n  = packed >> 10;
        const int old = packed & 1023;
        __syncthreads();   // protect LDS reuse across f-iterations
        const float rme = res[n*DD + tid] + cb[(long)old*DD + tid];
        rorig[tid] = rme;
        __syncthreads();
        float bd = 1e30f; int bi = 0;
        #pragma unroll
        for (int q = 0; q < 4; ++q) {
            const int code = tid + 256*q;
            const float* crow = &cb[(long)code*DD];
            float dot = 0.f;
            for (int d = 0; d < DD; ++d) dot += rorig[d]*crow[d];
            const float dist = c2[code] - 2.0f*dot;
            if (dist < bd || (dist == bd && code < bi)) { bd = dist; bi = code; }
        }
        sD[tid] = bd; sI[tid] = bi;
        __syncthreads();
        for (int s = 128; s; s >>= 1) {
            if (tid < s) {
                const float d2 = sD[tid + s]; const int i2 = sI[tid + s];
                if (d2 < sD[tid] || (d2 == sD[tid] && i2 < sI[tid])) { sD[tid] = d2; sI[tid] = i2; }
            }
            __syncthreads();
        }
        const int best = sI[0];
        if (best != old) {
            const float rn = rorig[tid] - cb[(long)best*DD + tid];
            const float ro = res[n*DD + tid];
            res[n*DD + tid] = rn;
            float delta = rn*rn - ro*ro;
            #pragma unroll
            for (int off = 32; off; off >>= 1) delta += __shfl_down(delta, off, 64);
            if ((tid & 63) == 0) atomicAdd(lossAcc, delta);
        }
    }
}

// ---------------------------------------------------------------------------
// Decoder: quant = z - res_final (z recomputed); conv1d to 1 channel + loss out.
// ---------------------------------------------------------------------------
__global__ __launch_bounds__(256) void decode_kernel(
    const float* __restrict__ x,  const float* __restrict__ ew,
    const float* __restrict__ eb, const float* __restrict__ res,
    const float* __restrict__ dw, const float* __restrict__ db,
    const float* __restrict__ lossAcc, float* __restrict__ out)
{
    const long n = (long)blockIdx.x * 4 + (threadIdx.x >> 6);
    const int lane = threadIdx.x & 63;
    const int t = (int)(n & (TT - 1));
    float sum = 0.0f;
    #pragma unroll
    for (int k = 0; k < 3; ++k) {
        const int tm = t + k - 1;
        if (tm < 0 || tm > TT - 1) continue;
        const long m = n + k - 1;
        const float xm = (tm > 0)      ? x[m - 1] : 0.0f;
        const float x0 = x[m];
        const float xp = (tm < TT - 1) ? x[m + 1] : 0.0f;
        #pragma unroll
        for (int q = 0; q < 4; ++q) {
            const int d = lane + 64 * q;
            const float z = eb[d] + ew[d*3]*xm + ew[d*3 + 1]*x0 + ew[d*3 + 2]*xp;
            const float quant = z - res[m * DD + d];
            sum += quant * dw[d*3 + k];
        }
    }
    #pragma unroll
    for (int off = 32; off; off >>= 1) sum += __shfl_down(sum, off, 64);
    if (lane == 0) out[n] = sum + db[0];
    if (blockIdx.x == 0 && threadIdx.x == 0)
        out[NN] = lossAcc[0] * (1.0f / ((float)NN * (float)DD));
}

// ---------------------------------------------------------------------------
// Workspace: d_ws = res 64MB + lossAcc(16B) + per-stage cbh 512KB (~64.5MB).
// d_out scratch until decode: [0..7]=flagCnt[8], [8..8199]=c2, [8200..]=flagList.
// ---------------------------------------------------------------------------
extern "C" void kernel_launch(void* const* d_in, const int* in_sizes, int n_in,
                              void* d_out, int out_size, void* d_ws, size_t ws_size,
                              hipStream_t stream)
{
    const float* x     = (const float*)d_in[0];
    const float* enc_w = (const float*)d_in[1];
    const float* enc_b = (const float*)d_in[2];
    const float* dec_w = (const float*)d_in[3];
    const float* dec_b = (const float*)d_in[4];
    const float* cbs   = (const float*)d_in[5];
    float* out = (float*)d_out;

    float*    res      = (float*)d_ws;               // [NN][DD] = 64 MB
    float*    lossAcc  = res + (size_t)NN * DD;      // 1 float (+pad)
    _Float16* cbh      = (_Float16*)(lossAcc + 4);   // [KC][DD] f16 = 512 KB
    int*      flagCnt  = (int*)out;                  // [QS] in d_out
    float*    c2       = out + 8;                    // [QS*KC] in d_out
    int*      flagList = (int*)(out + 8 + QS * KC);  // cap FLAGCAP in d_out

    hipLaunchKernelGGL(encode_init_kernel, dim3(NN / 16), dim3(256), 0, stream,
                       x, enc_w, enc_b, res, lossAcc, flagCnt);
    hipLaunchKernelGGL(c2_kernel, dim3(QS * KC / 4), dim3(256), 0, stream,
                       cbs, c2);
    for (int s = 0; s < QS; ++s) {
        hipLaunchKernelGGL(cb_prep_stage_kernel, dim3(KC * DD / 1024), dim3(256), 0, stream,
                           cbs + (size_t)s * KC * DD, cbh);
        hipLaunchKernelGGL(rvq_pass1_kernel, dim3(NN / 128), dim3(256), 0, stream,
                           cbs + (size_t)s * KC * DD, cbh,
                           c2 + (size_t)s * KC,
                           res, lossAcc, flagCnt + s, flagList);
        hipLaunchKernelGGL(recheck_kernel, dim3(256), dim3(256), 0, stream,
                           cbs + (size_t)s * KC * DD,
                           c2 + (size_t)s * KC,
                           res, lossAcc, flagCnt + s, flagList);
    }
    hipLaunchKernelGGL(decode_kernel, dim3(NN / 4), dim3(256), 0, stream,
                       x, enc_w, enc_b, res, dec_w, dec_b, lossAcc, out);
}

// Round 11
// 1615.580 us; speedup vs baseline: 1.3047x; 1.0094x over previous
//
#include <hip/hip_runtime.h>

#define QS 8
#define KC 1024
#define DD 256
#define TT 8192
#define NN 65536
#define TAU 0.06f
#define FLAGCAP 49152

typedef _Float16 half8 __attribute__((ext_vector_type(8)));
typedef _Float16 half4 __attribute__((ext_vector_type(4)));
typedef float f32x4 __attribute__((ext_vector_type(4)));

// async global->LDS DMA, 16B per lane, LDS dst = wave-uniform base + lane*16
__device__ __forceinline__ void gload_lds16(const _Float16* g, _Float16* l) {
    __builtin_amdgcn_global_load_lds(
        (const __attribute__((address_space(1))) void*)g,
        (__attribute__((address_space(3))) void*)l,
        16, 0, 0);
}

// ---------------------------------------------------------------------------
// Encoder: z = conv1d(x) -> res (token-major [N][256]); zero loss + flag cnts.
// ---------------------------------------------------------------------------
__global__ __launch_bounds__(256) void encode_init_kernel(
    const float* __restrict__ x, const float* __restrict__ ew,
    const float* __restrict__ eb, float* __restrict__ res,
    float* __restrict__ lossAcc, int* __restrict__ flagCnt)
{
    if (blockIdx.x == 0 && threadIdx.x == 0) *lossAcc = 0.0f;
    if (blockIdx.x == 0 && threadIdx.x < QS) flagCnt[threadIdx.x] = 0;
    const int d = threadIdx.x;                 // 256 == DD
    const float w0 = ew[d*3 + 0];
    const float w1 = ew[d*3 + 1];
    const float w2 = ew[d*3 + 2];
    const float b  = eb[d];
    #pragma unroll 4
    for (int tt = 0; tt < 16; ++tt) {
        const long n = (long)blockIdx.x * 16 + tt;   // grid = 4096
        const int t = (int)(n & (TT - 1));
        const float xm = (t > 0)      ? x[n - 1] : 0.0f;
        const float x0 = x[n];
        const float xp = (t < TT - 1) ? x[n + 1] : 0.0f;
        res[n * DD + d] = b + w0*xm + w1*x0 + w2*xp;
    }
}

// ---------------------------------------------------------------------------
// c2[s][k] = ||codebook[s][k]||^2 ; one wave per code.
// ---------------------------------------------------------------------------
__global__ __launch_bounds__(256) void c2_kernel(
    const float* __restrict__ cbs, float* __restrict__ c2)
{
    const int w = (int)((blockIdx.x * blockDim.x + threadIdx.x) >> 6);
    const int lane = threadIdx.x & 63;
    if (w >= QS * KC) return;
    const float* row = cbs + (long)w * DD;
    float s = 0.0f;
    #pragma unroll
    for (int q = 0; q < DD / 64; ++q) {
        const float v = row[lane + 64*q];
        s += v * v;
    }
    #pragma unroll
    for (int off = 32; off; off >>= 1) s += __shfl_down(s, off, 64);
    if (lane == 0) c2[w] = s;
}

// ---------------------------------------------------------------------------
// Per-stage codebook f16 hi plane: cbh[KC][DD] (512 KB).
// ---------------------------------------------------------------------------
__global__ __launch_bounds__(256) void cb_prep_stage_kernel(
    const float* __restrict__ cb, _Float16* __restrict__ cbh)
{
    const int i = (blockIdx.x * 256 + threadIdx.x) * 4;   // grid = KC*DD/1024
    const float4 v = *reinterpret_cast<const float4*>(&cb[i]);
    half4 hv;
    hv[0] = (_Float16)v.x; hv[1] = (_Float16)v.y;
    hv[2] = (_Float16)v.z; hv[3] = (_Float16)v.w;
    *reinterpret_cast<half4*>(&cbh[i]) = hv;
}

// ---------------------------------------------------------------------------
// Fused RVQ stage, f16 MFMA 2-term, global_load_lds staging (m97 pattern):
// round t: issue DMA for t+1 into buf^1, compute on buf (8 ds_read + 16 MFMA),
// one barrier (its vmcnt drain completes the DMA). No reg round-trip.
// ---------------------------------------------------------------------------
__global__ __launch_bounds__(256, 2) void rvq_pass1_kernel(
    const float* __restrict__ cb,      // [KC][DD] fp32 (epilogue gather)
    const _Float16* __restrict__ cbh,  // [KC][DD] f16 (this stage)
    const float* __restrict__ c2,      // [KC]
    float* __restrict__ res,           // [NN][DD]
    float* __restrict__ lossAcc,
    int* __restrict__ flagCnt,         // this stage
    int* __restrict__ flagList)        // shared list, cap FLAGCAP
{
    __shared__ __align__(16) _Float16 Bt[2][4096];  // [buf][(kchunk*64+code)*8] = 16 KB
    __shared__ int idxArr[128];

    const int tid = threadIdx.x;
    const int w   = tid >> 6;
    const int l   = tid & 63;
    const int l15 = l & 15;
    const int l4  = l >> 4;
    const long n0 = (long)blockIdx.x * 128;

    // ---- orientation probe (exact arithmetic; proven round 5/10) ----
    int tr;
    {
        half8 pa, pb;
        #pragma unroll
        for (int e = 0; e < 8; ++e) {
            pa[e] = (_Float16)l15;
            pb[e] = (_Float16)0.03125f;
        }
        f32x4 pacc = (f32x4){0.f, 0.f, 0.f, 0.f};
        pacc = __builtin_amdgcn_mfma_f32_16x16x32_f16(pa, pb, pacc, 0, 0, 0);
        const float p1 = __shfl(pacc[1], 0, 64);
        tr = (p1 < 0.5f) ? 1 : 0;
    }

    // ---- A fragments: token = n0 + w*32 + mt*16 + l15, k-run (l>>4)*8 ----
    half8 ah[2][8], al[2][8];
    #pragma unroll
    for (int mt = 0; mt < 2; ++mt) {
      #pragma unroll
      for (int kc = 0; kc < 8; ++kc) {
        const long n = n0 + w*32 + mt*16 + l15;
        const float* p = &res[n*DD + kc*32 + l4*8];
        const float4 v0 = *reinterpret_cast<const float4*>(p);
        const float4 v1 = *reinterpret_cast<const float4*>(p + 4);
        const float xv[8] = {v0.x, v0.y, v0.z, v0.w, v1.x, v1.y, v1.z, v1.w};
        half8 hv, lv;
        #pragma unroll
        for (int e = 0; e < 8; ++e) {
            const _Float16 hh = (_Float16)xv[e];
            hv[e] = hh;
            lv[e] = (_Float16)(xv[e] - (float)hh);
        }
        ah[mt][kc] = hv; al[mt][kc] = lv;
      }
    }

    float b1[8], b2[8]; int i1[8];
    #pragma unroll
    for (int r = 0; r < 8; ++r) { b1[r] = 1e30f; b2[r] = 1e30f; i1[r] = 0; }

    // DMA staging: chunk p = kchunk*64+code at LDS byte p*16.
    // thread tid covers p0 = tid (= w*64+l -> base w*1024B + lane*16B) and
    // p1 = tid+256 (-> base 4096B + w*1024B + lane*16B): exactly the HW's
    // wave-uniform-base + lane*16 pattern. Global src is per-lane.
    auto stage = [&](int t, int buf) {
        const int cg = t >> 2, kp = t & 3;
        const long o0 = (long)(cg*64 + l)*DD + kp*64 + w*8;
        const long o1 = (long)(cg*64 + l)*DD + kp*64 + (w + 4)*8;
        gload_lds16(cbh + o0, &Bt[buf][w*512]);
        gload_lds16(cbh + o1, &Bt[buf][2048 + w*512]);
    };

    stage(0, 0);
    __syncthreads();   // drains vmcnt -> tile 0 resident

    for (int cg = 0; cg < 16; ++cg) {
      f32x4 acc[2][4];
      #pragma unroll
      for (int mt = 0; mt < 2; ++mt)
        #pragma unroll
        for (int nt = 0; nt < 4; ++nt)
          acc[mt][nt] = (f32x4){0.f, 0.f, 0.f, 0.f};

      for (int kp = 0; kp < 4; ++kp) {
        const int t = cg*4 + kp, buf = t & 1;
        if (t < 63) stage(t + 1, buf ^ 1);   // async DMA, no reg round-trip

        #pragma unroll
        for (int kc2 = 0; kc2 < 2; ++kc2) {
          const int kc = kp*2 + kc2;
          #pragma unroll
          for (int nt = 0; nt < 4; ++nt) {
            const int slot = ((kc2*4 + l4)*64 + nt*16 + l15)*8;
            const half8 bh = *reinterpret_cast<const half8*>(&Bt[buf][slot]);
            #pragma unroll
            for (int mt = 0; mt < 2; ++mt) {
              acc[mt][nt] = __builtin_amdgcn_mfma_f32_16x16x32_f16(ah[mt][kc], bh, acc[mt][nt], 0, 0, 0);
              acc[mt][nt] = __builtin_amdgcn_mfma_f32_16x16x32_f16(al[mt][kc], bh, acc[mt][nt], 0, 0, 0);
            }
          }
        }

        __syncthreads();   // one barrier/round: drains DMA + orders LDS reuse
      }

      if (tr == 0) {
        // token on reg side (row=l4*4+j), code on lane side (col=l15)
        #pragma unroll
        for (int nt = 0; nt < 4; ++nt) {
          const int code = cg*64 + nt*16 + l15;
          const float cc = c2[code];
          #pragma unroll
          for (int mt = 0; mt < 2; ++mt) {
            #pragma unroll
            for (int j = 0; j < 4; ++j) {
              const float dist = cc - 2.0f*acc[mt][nt][j];
              const int r = mt*4 + j;
              if (dist < b1[r])      { b2[r] = b1[r]; b1[r] = dist; i1[r] = code; }
              else if (dist < b2[r]) { b2[r] = dist; }
            }
          }
        }
      } else {
        // token on lane side (l15), code on reg side (l4*4+j)
        #pragma unroll
        for (int nt = 0; nt < 4; ++nt) {
          #pragma unroll
          for (int j = 0; j < 4; ++j) {
            const int code = cg*64 + nt*16 + l4*4 + j;
            const float cc = c2[code];
            #pragma unroll
            for (int mt = 0; mt < 2; ++mt) {
              const float dist = cc - 2.0f*acc[mt][nt][j];
              if (dist < b1[mt])      { b2[mt] = b1[mt]; b1[mt] = dist; i1[mt] = code; }
              else if (dist < b2[mt]) { b2[mt] = dist; }
            }
          }
        }
      }
    }

    if (tr == 0) {
      #pragma unroll
      for (int m = 1; m < 16; m <<= 1) {
        #pragma unroll
        for (int r = 0; r < 8; ++r) {
          const float ob1 = __shfl_xor(b1[r], m, 64);
          const float ob2 = __shfl_xor(b2[r], m, 64);
          const int   oi1 = __shfl_xor(i1[r], m, 64);
          const float nb2 = fminf(fminf(b2[r], ob2), fmaxf(b1[r], ob1));
          if (ob1 < b1[r] || (ob1 == b1[r] && oi1 < i1[r])) { b1[r] = ob1; i1[r] = oi1; }
          b2[r] = nb2;
        }
      }
      if (l15 == 0) {
        #pragma unroll
        for (int mt = 0; mt < 2; ++mt)
          #pragma unroll
          for (int j = 0; j < 4; ++j) {
            const int r = mt*4 + j;
            const int row = w*32 + mt*16 + l4*4 + j;
            idxArr[row] = i1[r];
            if (b2[r] - b1[r] < TAU) {
              const int pos = atomicAdd(flagCnt, 1);
              if (pos < FLAGCAP)
                flagList[pos] = (int)(((n0 + row) << 10) | (unsigned)i1[r]);
            }
          }
      }
    } else {
      #pragma unroll
      for (int m = 16; m <= 32; m <<= 1) {
        #pragma unroll
        for (int r = 0; r < 2; ++r) {
          const float ob1 = __shfl_xor(b1[r], m, 64);
          const float ob2 = __shfl_xor(b2[r], m, 64);
          const int   oi1 = __shfl_xor(i1[r], m, 64);
          const float nb2 = fminf(fminf(b2[r], ob2), fmaxf(b1[r], ob1));
          if (ob1 < b1[r] || (ob1 == b1[r] && oi1 < i1[r])) { b1[r] = ob1; i1[r] = oi1; }
          b2[r] = nb2;
        }
      }
      if (l4 == 0) {
        #pragma unroll
        for (int mt = 0; mt < 2; ++mt) {
          const int row = w*32 + mt*16 + l15;
          idxArr[row] = i1[mt];
          if (b2[mt] - b1[mt] < TAU) {
            const int pos = atomicAdd(flagCnt, 1);
            if (pos < FLAGCAP)
              flagList[pos] = (int)(((n0 + row) << 10) | (unsigned)i1[mt]);
          }
        }
      }
    }
    __syncthreads();

    // residual update in place + commitment-loss partial (float4 vectorized)
    float lsum = 0.0f;
    const int rw = tid >> 6;        // row-within-quad
    const int cc4 = (tid & 63) * 4; // column base
    #pragma unroll 4
    for (int it = 0; it < 32; ++it) {
        const int r = it*4 + rw;
        const long n = n0 + r;
        const int ix = idxArr[r];
        float4 rv = *reinterpret_cast<const float4*>(&res[n*DD + cc4]);
        const float4 cv = *reinterpret_cast<const float4*>(&cb[(long)ix*DD + cc4]);
        rv.x -= cv.x; rv.y -= cv.y; rv.z -= cv.z; rv.w -= cv.w;
        *reinterpret_cast<float4*>(&res[n*DD + cc4]) = rv;
        lsum += rv.x*rv.x + rv.y*rv.y + rv.z*rv.z + rv.w*rv.w;
    }
    #pragma unroll
    for (int off = 32; off; off >>= 1) lsum += __shfl_down(lsum, off, 64);
    if (l == 0) atomicAdd(lossAcc, lsum);
}

// ---------------------------------------------------------------------------
// Exact fp32 recheck for margin-flagged tokens. Fixed grid, grid-strided.
// ---------------------------------------------------------------------------
__global__ __launch_bounds__(256) void recheck_kernel(
    const float* __restrict__ cb, const float* __restrict__ c2,
    float* __restrict__ res, float* __restrict__ lossAcc,
    const int* __restrict__ flagCnt, const int* __restrict__ flagList)
{
    __shared__ float rorig[DD];
    __shared__ float sD[256];
    __shared__ int   sI[256];
    const int cnt = min(*flagCnt, FLAGCAP);
    const int tid = threadIdx.x;
    for (int f = blockIdx.x; f < cnt; f += gridDim.x) {
        const int packed = flagList[f];
        const long n  = packed >> 10;
        const int old = packed & 1023;
        __syncthreads();   // protect LDS reuse across f-iterations
        const float rme = res[n*DD + tid] + cb[(long)old*DD + tid];
        rorig[tid] = rme;
        __syncthreads();
        float bd = 1e30f; int bi = 0;
        #pragma unroll
        for (int q = 0; q < 4; ++q) {
            const int code = tid + 256*q;
            const float* crow = &cb[(long)code*DD];
            float dot = 0.f;
            for (int d = 0; d < DD; ++d) dot += rorig[d]*crow[d];
            const float dist = c2[code] - 2.0f*dot;
            if (dist < bd || (dist == bd && code < bi)) { bd = dist; bi = code; }
        }
        sD[tid] = bd; sI[tid] = bi;
        __syncthreads();
        for (int s = 128; s; s >>= 1) {
            if (tid < s) {
                const float d2 = sD[tid + s]; const int i2 = sI[tid + s];
                if (d2 < sD[tid] || (d2 == sD[tid] && i2 < sI[tid])) { sD[tid] = d2; sI[tid] = i2; }
            }
            __syncthreads();
        }
        const int best = sI[0];
        if (best != old) {
            const float rn = rorig[tid] - cb[(long)best*DD + tid];
            const float ro = res[n*DD + tid];
            res[n*DD + tid] = rn;
            float delta = rn*rn - ro*ro;
            #pragma unroll
            for (int off = 32; off; off >>= 1) delta += __shfl_down(delta, off, 64);
            if ((tid & 63) == 0) atomicAdd(lossAcc, delta);
        }
    }
}

// ---------------------------------------------------------------------------
// Decoder: quant = z - res_final (z recomputed); conv1d to 1 channel + loss out.
// ---------------------------------------------------------------------------
__global__ __launch_bounds__(256) void decode_kernel(
    const float* __restrict__ x,  const float* __restrict__ ew,
    const float* __restrict__ eb, const float* __restrict__ res,
    const float* __restrict__ dw, const float* __restrict__ db,
    const float* __restrict__ lossAcc, float* __restrict__ out)
{
    const long n = (long)blockIdx.x * 4 + (threadIdx.x >> 6);
    const int lane = threadIdx.x & 63;
    const int t = (int)(n & (TT - 1));
    float sum = 0.0f;
    #pragma unroll
    for (int k = 0; k < 3; ++k) {
        const int tm = t + k - 1;
        if (tm < 0 || tm > TT - 1) continue;
        const long m = n + k - 1;
        const float xm = (tm > 0)      ? x[m - 1] : 0.0f;
        const float x0 = x[m];
        const float xp = (tm < TT - 1) ? x[m + 1] : 0.0f;
        #pragma unroll
        for (int q = 0; q < 4; ++q) {
            const int d = lane + 64 * q;
            const float z = eb[d] + ew[d*3]*xm + ew[d*3 + 1]*x0 + ew[d*3 + 2]*xp;
            const float quant = z - res[m * DD + d];
            sum += quant * dw[d*3 + k];
        }
    }
    #pragma unroll
    for (int off = 32; off; off >>= 1) sum += __shfl_down(sum, off, 64);
    if (lane == 0) out[n] = sum + db[0];
    if (blockIdx.x == 0 && threadIdx.x == 0)
        out[NN] = lossAcc[0] * (1.0f / ((float)NN * (float)DD));
}

// ---------------------------------------------------------------------------
// Workspace: d_ws = res 64MB + lossAcc(16B) + per-stage cbh 512KB (~64.5MB).
// d_out scratch until decode: [0..7]=flagCnt[8], [8..8199]=c2, [8200..]=flagList.
// ---------------------------------------------------------------------------
extern "C" void kernel_launch(void* const* d_in, const int* in_sizes, int n_in,
                              void* d_out, int out_size, void* d_ws, size_t ws_size,
                              hipStream_t stream)
{
    const float* x     = (const float*)d_in[0];
    const float* enc_w = (const float*)d_in[1];
    const float* enc_b = (const float*)d_in[2];
    const float* dec_w = (const float*)d_in[3];
    const float* dec_b = (const float*)d_in[4];
    const float* cbs   = (const float*)d_in[5];
    float* out = (float*)d_out;

    float*    res      = (float*)d_ws;               // [NN][DD] = 64 MB
    float*    lossAcc  = res + (size_t)NN * DD;      // 1 float (+pad)
    _Float16* cbh      = (_Float16*)(lossAcc + 4);   // [KC][DD] f16 = 512 KB
    int*      flagCnt  = (int*)out;                  // [QS] in d_out
    float*    c2       = out + 8;                    // [QS*KC] in d_out
    int*      flagList = (int*)(out + 8 + QS * KC);  // cap FLAGCAP in d_out

    hipLaunchKernelGGL(encode_init_kernel, dim3(NN / 16), dim3(256), 0, stream,
                       x, enc_w, enc_b, res, lossAcc, flagCnt);
    hipLaunchKernelGGL(c2_kernel, dim3(QS * KC / 4), dim3(256), 0, stream,
                       cbs, c2);
    for (int s = 0; s < QS; ++s) {
        hipLaunchKernelGGL(cb_prep_stage_kernel, dim3(KC * DD / 1024), dim3(256), 0, stream,
                           cbs + (size_t)s * KC * DD, cbh);
        hipLaunchKernelGGL(rvq_pass1_kernel, dim3(NN / 128), dim3(256), 0, stream,
                           cbs + (size_t)s * KC * DD, cbh,
                           c2 + (size_t)s * KC,
                           res, lossAcc, flagCnt + s, flagList);
        hipLaunchKernelGGL(recheck_kernel, dim3(256), dim3(256), 0, stream,
                           cbs + (size_t)s * KC * DD,
                           c2 + (size_t)s * KC,
                           res, lossAcc, flagCnt + s, flagList);
    }
    hipLaunchKernelGGL(decode_kernel, dim3(NN / 4), dim3(256), 0, stream,
                       x, enc_w, enc_b, res, dec_w, dec_b, lossAcc, out);
}

// Round 12
// 1586.580 us; speedup vs baseline: 1.3285x; 1.0183x over previous
//
#include <hip/hip_runtime.h>

#define QS 8
#define KC 1024
#define DD 256
#define TT 8192
#define NN 65536
#define TAU 0.06f
#define FLAGCAP 49152

typedef _Float16 half8 __attribute__((ext_vector_type(8)));
typedef _Float16 half4 __attribute__((ext_vector_type(4)));
typedef float f32x4 __attribute__((ext_vector_type(4)));

// async global->LDS DMA, 16B per lane, LDS dst = wave-uniform base + lane*16
__device__ __forceinline__ void gload_lds16(const _Float16* g, _Float16* l) {
    __builtin_amdgcn_global_load_lds(
        (const __attribute__((address_space(1))) void*)g,
        (__attribute__((address_space(3))) void*)l,
        16, 0, 0);
}

// ---------------------------------------------------------------------------
// Encoder: z = conv1d(x) -> res (token-major [N][256]); zero loss + flag cnts.
// ---------------------------------------------------------------------------
__global__ __launch_bounds__(256) void encode_init_kernel(
    const float* __restrict__ x, const float* __restrict__ ew,
    const float* __restrict__ eb, float* __restrict__ res,
    float* __restrict__ lossAcc, int* __restrict__ flagCnt)
{
    if (blockIdx.x == 0 && threadIdx.x == 0) *lossAcc = 0.0f;
    if (blockIdx.x == 0 && threadIdx.x < QS) flagCnt[threadIdx.x] = 0;
    const int d = threadIdx.x;                 // 256 == DD
    const float w0 = ew[d*3 + 0];
    const float w1 = ew[d*3 + 1];
    const float w2 = ew[d*3 + 2];
    const float b  = eb[d];
    #pragma unroll 4
    for (int tt = 0; tt < 16; ++tt) {
        const long n = (long)blockIdx.x * 16 + tt;   // grid = 4096
        const int t = (int)(n & (TT - 1));
        const float xm = (t > 0)      ? x[n - 1] : 0.0f;
        const float x0 = x[n];
        const float xp = (t < TT - 1) ? x[n + 1] : 0.0f;
        res[n * DD + d] = b + w0*xm + w1*x0 + w2*xp;
    }
}

// ---------------------------------------------------------------------------
// c2[s][k] = ||codebook[s][k]||^2 ; one wave per code.
// ---------------------------------------------------------------------------
__global__ __launch_bounds__(256) void c2_kernel(
    const float* __restrict__ cbs, float* __restrict__ c2)
{
    const int w = (int)((blockIdx.x * blockDim.x + threadIdx.x) >> 6);
    const int lane = threadIdx.x & 63;
    if (w >= QS * KC) return;
    const float* row = cbs + (long)w * DD;
    float s = 0.0f;
    #pragma unroll
    for (int q = 0; q < DD / 64; ++q) {
        const float v = row[lane + 64*q];
        s += v * v;
    }
    #pragma unroll
    for (int off = 32; off; off >>= 1) s += __shfl_down(s, off, 64);
    if (lane == 0) c2[w] = s;
}

// ---------------------------------------------------------------------------
// Per-stage codebook f16, PRE-SWIZZLED into tile-major fragment order:
// tile t = cg*4+kp (64 tiles x 4096 f16); chunk p = kchunk*64+code at t*4096+p*8
// holds cb[cg*64+code][kp*64+kchunk*8 .. +8]. This makes pass1 staging reads
// LINEAR in lane order (the gather moves here, once per stage).
// ---------------------------------------------------------------------------
__global__ __launch_bounds__(256) void cb_prep_stage_kernel(
    const float* __restrict__ cb, _Float16* __restrict__ cbh)
{
    const int t = blockIdx.x;          // grid = 64 tiles
    const int cg = t >> 2, kp = t & 3;
    #pragma unroll
    for (int q = 0; q < 2; ++q) {
        const int p = threadIdx.x + 256*q;
        const int code = p & 63, kchunk = p >> 6;
        const float* src = &cb[(long)(cg*64 + code)*DD + kp*64 + kchunk*8];
        const float4 v0 = *reinterpret_cast<const float4*>(src);
        const float4 v1 = *reinterpret_cast<const float4*>(src + 4);
        half8 hv;
        hv[0]=(_Float16)v0.x; hv[1]=(_Float16)v0.y;
        hv[2]=(_Float16)v0.z; hv[3]=(_Float16)v0.w;
        hv[4]=(_Float16)v1.x; hv[5]=(_Float16)v1.y;
        hv[6]=(_Float16)v1.z; hv[7]=(_Float16)v1.w;
        *reinterpret_cast<half8*>(&cbh[(long)t*4096 + p*8]) = hv;
    }
}

// ---------------------------------------------------------------------------
// Fused RVQ stage, f16 MFMA 2-term, global_load_lds staging with COALESCED
// source (pre-swizzled codebook): lane i reads consecutive 16B. One barrier
// per round; LDS read side identical to rounds 10/11 (verified).
// ---------------------------------------------------------------------------
__global__ __launch_bounds__(256, 2) void rvq_pass1_kernel(
    const float* __restrict__ cb,      // [KC][DD] fp32 (epilogue gather)
    const _Float16* __restrict__ cbh,  // [64 tiles][4096] f16 swizzled
    const float* __restrict__ c2,      // [KC]
    float* __restrict__ res,           // [NN][DD]
    float* __restrict__ lossAcc,
    int* __restrict__ flagCnt,         // this stage
    int* __restrict__ flagList)        // shared list, cap FLAGCAP
{
    __shared__ __align__(16) _Float16 Bt[2][4096];  // [buf][(kchunk*64+code)*8] = 16 KB
    __shared__ int idxArr[128];

    const int tid = threadIdx.x;
    const int w   = tid >> 6;
    const int l   = tid & 63;
    const int l15 = l & 15;
    const int l4  = l >> 4;
    const long n0 = (long)blockIdx.x * 128;

    // ---- orientation probe (exact arithmetic; proven rounds 5/10/11) ----
    int tr;
    {
        half8 pa, pb;
        #pragma unroll
        for (int e = 0; e < 8; ++e) {
            pa[e] = (_Float16)l15;
            pb[e] = (_Float16)0.03125f;
        }
        f32x4 pacc = (f32x4){0.f, 0.f, 0.f, 0.f};
        pacc = __builtin_amdgcn_mfma_f32_16x16x32_f16(pa, pb, pacc, 0, 0, 0);
        const float p1 = __shfl(pacc[1], 0, 64);
        tr = (p1 < 0.5f) ? 1 : 0;
    }

    // ---- A fragments: token = n0 + w*32 + mt*16 + l15, k-run (l>>4)*8 ----
    half8 ah[2][8], al[2][8];
    #pragma unroll
    for (int mt = 0; mt < 2; ++mt) {
      #pragma unroll
      for (int kc = 0; kc < 8; ++kc) {
        const long n = n0 + w*32 + mt*16 + l15;
        const float* p = &res[n*DD + kc*32 + l4*8];
        const float4 v0 = *reinterpret_cast<const float4*>(p);
        const float4 v1 = *reinterpret_cast<const float4*>(p + 4);
        const float xv[8] = {v0.x, v0.y, v0.z, v0.w, v1.x, v1.y, v1.z, v1.w};
        half8 hv, lv;
        #pragma unroll
        for (int e = 0; e < 8; ++e) {
            const _Float16 hh = (_Float16)xv[e];
            hv[e] = hh;
            lv[e] = (_Float16)(xv[e] - (float)hh);
        }
        ah[mt][kc] = hv; al[mt][kc] = lv;
      }
    }

    float b1[8], b2[8]; int i1[8];
    #pragma unroll
    for (int r = 0; r < 8; ++r) { b1[r] = 1e30f; b2[r] = 1e30f; i1[r] = 0; }

    // COALESCED DMA staging: tile t is 4096 contiguous f16; thread tid covers
    // chunks p0 = tid, p1 = tid+256; global offset = p*16B (linear in lane),
    // LDS dst = wave-uniform base + lane*16B. 4-line coalesced per instr.
    auto stage = [&](int t, int buf) {
        const _Float16* src = cbh + (long)t*4096;
        gload_lds16(src + ((w*64 + l)*8),        &Bt[buf][w*512]);
        gload_lds16(src + ((256 + w*64 + l)*8),  &Bt[buf][2048 + w*512]);
    };

    stage(0, 0);
    __syncthreads();   // drains vmcnt -> tile 0 resident

    for (int cg = 0; cg < 16; ++cg) {
      f32x4 acc[2][4];
      #pragma unroll
      for (int mt = 0; mt < 2; ++mt)
        #pragma unroll
        for (int nt = 0; nt < 4; ++nt)
          acc[mt][nt] = (f32x4){0.f, 0.f, 0.f, 0.f};

      for (int kp = 0; kp < 4; ++kp) {
        const int t = cg*4 + kp, buf = t & 1;
        if (t < 63) stage(t + 1, buf ^ 1);   // async coalesced DMA

        #pragma unroll
        for (int kc2 = 0; kc2 < 2; ++kc2) {
          const int kc = kp*2 + kc2;
          #pragma unroll
          for (int nt = 0; nt < 4; ++nt) {
            const int slot = ((kc2*4 + l4)*64 + nt*16 + l15)*8;
            const half8 bh = *reinterpret_cast<const half8*>(&Bt[buf][slot]);
            #pragma unroll
            for (int mt = 0; mt < 2; ++mt) {
              acc[mt][nt] = __builtin_amdgcn_mfma_f32_16x16x32_f16(ah[mt][kc], bh, acc[mt][nt], 0, 0, 0);
              acc[mt][nt] = __builtin_amdgcn_mfma_f32_16x16x32_f16(al[mt][kc], bh, acc[mt][nt], 0, 0, 0);
            }
          }
        }

        __syncthreads();   // one barrier/round: drains DMA + orders LDS reuse
      }

      if (tr == 0) {
        // token on reg side (row=l4*4+j), code on lane side (col=l15)
        #pragma unroll
        for (int nt = 0; nt < 4; ++nt) {
          const int code = cg*64 + nt*16 + l15;
          const float cc = c2[code];
          #pragma unroll
          for (int mt = 0; mt < 2; ++mt) {
            #pragma unroll
            for (int j = 0; j < 4; ++j) {
              const float dist = cc - 2.0f*acc[mt][nt][j];
              const int r = mt*4 + j;
              if (dist < b1[r])      { b2[r] = b1[r]; b1[r] = dist; i1[r] = code; }
              else if (dist < b2[r]) { b2[r] = dist; }
            }
          }
        }
      } else {
        // token on lane side (l15), code on reg side (l4*4+j)
        #pragma unroll
        for (int nt = 0; nt < 4; ++nt) {
          #pragma unroll
          for (int j = 0; j < 4; ++j) {
            const int code = cg*64 + nt*16 + l4*4 + j;
            const float cc = c2[code];
            #pragma unroll
            for (int mt = 0; mt < 2; ++mt) {
              const float dist = cc - 2.0f*acc[mt][nt][j];
              if (dist < b1[mt])      { b2[mt] = b1[mt]; b1[mt] = dist; i1[mt] = code; }
              else if (dist < b2[mt]) { b2[mt] = dist; }
            }
          }
        }
      }
    }

    if (tr == 0) {
      #pragma unroll
      for (int m = 1; m < 16; m <<= 1) {
        #pragma unroll
        for (int r = 0; r < 8; ++r) {
          const float ob1 = __shfl_xor(b1[r], m, 64);
          const float ob2 = __shfl_xor(b2[r], m, 64);
          const int   oi1 = __shfl_xor(i1[r], m, 64);
          const float nb2 = fminf(fminf(b2[r], ob2), fmaxf(b1[r], ob1));
          if (ob1 < b1[r] || (ob1 == b1[r] && oi1 < i1[r])) { b1[r] = ob1; i1[r] = oi1; }
          b2[r] = nb2;
        }
      }
      if (l15 == 0) {
        #pragma unroll
        for (int mt = 0; mt < 2; ++mt)
          #pragma unroll
          for (int j = 0; j < 4; ++j) {
            const int r = mt*4 + j;
            const int row = w*32 + mt*16 + l4*4 + j;
            idxArr[row] = i1[r];
            if (b2[r] - b1[r] < TAU) {
              const int pos = atomicAdd(flagCnt, 1);
              if (pos < FLAGCAP)
                flagList[pos] = (int)(((n0 + row) << 10) | (unsigned)i1[r]);
            }
          }
      }
    } else {
      #pragma unroll
      for (int m = 16; m <= 32; m <<= 1) {
        #pragma unroll
        for (int r = 0; r < 2; ++r) {
          const float ob1 = __shfl_xor(b1[r], m, 64);
          const float ob2 = __shfl_xor(b2[r], m, 64);
          const int   oi1 = __shfl_xor(i1[r], m, 64);
          const float nb2 = fminf(fminf(b2[r], ob2), fmaxf(b1[r], ob1));
          if (ob1 < b1[r] || (ob1 == b1[r] && oi1 < i1[r])) { b1[r] = ob1; i1[r] = oi1; }
          b2[r] = nb2;
        }
      }
      if (l4 == 0) {
        #pragma unroll
        for (int mt = 0; mt < 2; ++mt) {
          const int row = w*32 + mt*16 + l15;
          idxArr[row] = i1[mt];
          if (b2[mt] - b1[mt] < TAU) {
            const int pos = atomicAdd(flagCnt, 1);
            if (pos < FLAGCAP)
              flagList[pos] = (int)(((n0 + row) << 10) | (unsigned)i1[mt]);
          }
        }
      }
    }
    __syncthreads();

    // residual update in place + commitment-loss partial (float4 vectorized)
    float lsum = 0.0f;
    const int rw = tid >> 6;        // row-within-quad
    const int cc4 = (tid & 63) * 4; // column base
    #pragma unroll 4
    for (int it = 0; it < 32; ++it) {
        const int r = it*4 + rw;
        const long n = n0 + r;
        const int ix = idxArr[r];
        float4 rv = *reinterpret_cast<const float4*>(&res[n*DD + cc4]);
        const float4 cv = *reinterpret_cast<const float4*>(&cb[(long)ix*DD + cc4]);
        rv.x -= cv.x; rv.y -= cv.y; rv.z -= cv.z; rv.w -= cv.w;
        *reinterpret_cast<float4*>(&res[n*DD + cc4]) = rv;
        lsum += rv.x*rv.x + rv.y*rv.y + rv.z*rv.z + rv.w*rv.w;
    }
    #pragma unroll
    for (int off = 32; off; off >>= 1) lsum += __shfl_down(lsum, off, 64);
    if (l == 0) atomicAdd(lossAcc, lsum);
}

// ---------------------------------------------------------------------------
// Exact fp32 recheck for margin-flagged tokens. Fixed grid, grid-strided.
// ---------------------------------------------------------------------------
__global__ __launch_bounds__(256) void recheck_kernel(
    const float* __restrict__ cb, const float* __restrict__ c2,
    float* __restrict__ res, float* __restrict__ lossAcc,
    const int* __restrict__ flagCnt, const int* __restrict__ flagList)
{
    __shared__ float rorig[DD];
    __shared__ float sD[256];
    __shared__ int   sI[256];
    const int cnt = min(*flagCnt, FLAGCAP);
    const int tid = threadIdx.x;
    for (int f = blockIdx.x; f < cnt; f += gridDim.x) {
        const int packed = flagList[f];
        const long n  = packed >> 10;
        const int old = packed & 1023;
        __syncthreads();   // protect LDS reuse across f-iterations
        const float rme = res[n*DD + tid] + cb[(long)old*DD + tid];
        rorig[tid] = rme;
        __syncthreads();
        float bd = 1e30f; int bi = 0;
        #pragma unroll
        for (int q = 0; q < 4; ++q) {
            const int code = tid + 256*q;
            const float* crow = &cb[(long)code*DD];
            float dot = 0.f;
            for (int d = 0; d < DD; ++d) dot += rorig[d]*crow[d];
            const float dist = c2[code] - 2.0f*dot;
            if (dist < bd || (dist == bd && code < bi)) { bd = dist; bi = code; }
        }
        sD[tid] = bd; sI[tid] = bi;
        __syncthreads();
        for (int s = 128; s; s >>= 1) {
            if (tid < s) {
                const float d2 = sD[tid + s]; const int i2 = sI[tid + s];
                if (d2 < sD[tid] || (d2 == sD[tid] && i2 < sI[tid])) { sD[tid] = d2; sI[tid] = i2; }
            }
            __syncthreads();
        }
        const int best = sI[0];
        if (best != old) {
            const float rn = rorig[tid] - cb[(long)best*DD + tid];
            const float ro = res[n*DD + tid];
            res[n*DD + tid] = rn;
            float delta = rn*rn - ro*ro;
            #pragma unroll
            for (int off = 32; off; off >>= 1) delta += __shfl_down(delta, off, 64);
            if ((tid & 63) == 0) atomicAdd(lossAcc, delta);
        }
    }
}

// ---------------------------------------------------------------------------
// Decoder: quant = z - res_final (z recomputed); conv1d to 1 channel + loss out.
// ---------------------------------------------------------------------------
__global__ __launch_bounds__(256) void decode_kernel(
    const float* __restrict__ x,  const float* __restrict__ ew,
    const float* __restrict__ eb, const float* __restrict__ res,
    const float* __restrict__ dw, const float* __restrict__ db,
    const float* __restrict__ lossAcc, float* __restrict__ out)
{
    const long n = (long)blockIdx.x * 4 + (threadIdx.x >> 6);
    const int lane = threadIdx.x & 63;
    const int t = (int)(n & (TT - 1));
    float sum = 0.0f;
    #pragma unroll
    for (int k = 0; k < 3; ++k) {
        const int tm = t + k - 1;
        if (tm < 0 || tm > TT - 1) continue;
        const long m = n + k - 1;
        const float xm = (tm > 0)      ? x[m - 1] : 0.0f;
        const float x0 = x[m];
        const float xp = (tm < TT - 1) ? x[m + 1] : 0.0f;
        #pragma unroll
        for (int q = 0; q < 4; ++q) {
            const int d = lane + 64 * q;
            const float z = eb[d] + ew[d*3]*xm + ew[d*3 + 1]*x0 + ew[d*3 + 2]*xp;
            const float quant = z - res[m * DD + d];
            sum += quant * dw[d*3 + k];
        }
    }
    #pragma unroll
    for (int off = 32; off; off >>= 1) sum += __shfl_down(sum, off, 64);
    if (lane == 0) out[n] = sum + db[0];
    if (blockIdx.x == 0 && threadIdx.x == 0)
        out[NN] = lossAcc[0] * (1.0f / ((float)NN * (float)DD));
}

// ---------------------------------------------------------------------------
// Workspace: d_ws = res 64MB + lossAcc(16B) + per-stage cbh 512KB (~64.5MB).
// d_out scratch until decode: [0..7]=flagCnt[8], [8..8199]=c2, [8200..]=flagList.
// ---------------------------------------------------------------------------
extern "C" void kernel_launch(void* const* d_in, const int* in_sizes, int n_in,
                              void* d_out, int out_size, void* d_ws, size_t ws_size,
                              hipStream_t stream)
{
    const float* x     = (const float*)d_in[0];
    const float* enc_w = (const float*)d_in[1];
    const float* enc_b = (const float*)d_in[2];
    const float* dec_w = (const float*)d_in[3];
    const float* dec_b = (const float*)d_in[4];
    const float* cbs   = (const float*)d_in[5];
    float* out = (float*)d_out;

    float*    res      = (float*)d_ws;               // [NN][DD] = 64 MB
    float*    lossAcc  = res + (size_t)NN * DD;      // 1 float (+pad)
    _Float16* cbh      = (_Float16*)(lossAcc + 4);   // [64][4096] f16 = 512 KB
    int*      flagCnt  = (int*)out;                  // [QS] in d_out
    float*    c2       = out + 8;                    // [QS*KC] in d_out
    int*      flagList = (int*)(out + 8 + QS * KC);  // cap FLAGCAP in d_out

    hipLaunchKernelGGL(encode_init_kernel, dim3(NN / 16), dim3(256), 0, stream,
                       x, enc_w, enc_b, res, lossAcc, flagCnt);
    hipLaunchKernelGGL(c2_kernel, dim3(QS * KC / 4), dim3(256), 0, stream,
                       cbs, c2);
    for (int s = 0; s < QS; ++s) {
        hipLaunchKernelGGL(cb_prep_stage_kernel, dim3(64), dim3(256), 0, stream,
                           cbs + (size_t)s * KC * DD, cbh);
        hipLaunchKernelGGL(rvq_pass1_kernel, dim3(NN / 128), dim3(256), 0, stream,
                           cbs + (size_t)s * KC * DD, cbh,
                           c2 + (size_t)s * KC,
                           res, lossAcc, flagCnt + s, flagList);
        hipLaunchKernelGGL(recheck_kernel, dim3(256), dim3(256), 0, stream,
                           cbs + (size_t)s * KC * DD,
                           c2 + (size_t)s * KC,
                           res, lossAcc, flagCnt + s, flagList);
    }
    hipLaunchKernelGGL(decode_kernel, dim3(NN / 4), dim3(256), 0, stream,
                       x, enc_w, enc_b, res, dec_w, dec_b, lossAcc, out);
}

// Round 13
// 1506.927 us; speedup vs baseline: 1.3988x; 1.0529x over previous
//
#include <hip/hip_runtime.h>

#define QS 8
#define KC 1024
#define DD 256
#define TT 8192
#define NN 65536
#define TAU 0.06f
#define FLAGCAP 49152

typedef _Float16 half8 __attribute__((ext_vector_type(8)));
typedef float f32x4 __attribute__((ext_vector_type(4)));

// async global->LDS DMA, 16B per lane, LDS dst = wave-uniform base + lane*16
__device__ __forceinline__ void gload_lds16(const _Float16* g, _Float16* l) {
    __builtin_amdgcn_global_load_lds(
        (const __attribute__((address_space(1))) void*)g,
        (__attribute__((address_space(3))) void*)l,
        16, 0, 0);
}

// ---------------------------------------------------------------------------
// Encoder: z = conv1d(x) -> res (token-major [N][256]); zero loss + flag cnts.
// ---------------------------------------------------------------------------
__global__ __launch_bounds__(256) void encode_init_kernel(
    const float* __restrict__ x, const float* __restrict__ ew,
    const float* __restrict__ eb, float* __restrict__ res,
    float* __restrict__ lossAcc, int* __restrict__ flagCnt)
{
    if (blockIdx.x == 0 && threadIdx.x == 0) *lossAcc = 0.0f;
    if (blockIdx.x == 0 && threadIdx.x < QS) flagCnt[threadIdx.x] = 0;
    const int d = threadIdx.x;                 // 256 == DD
    const float w0 = ew[d*3 + 0];
    const float w1 = ew[d*3 + 1];
    const float w2 = ew[d*3 + 2];
    const float b  = eb[d];
    #pragma unroll 4
    for (int tt = 0; tt < 16; ++tt) {
        const long n = (long)blockIdx.x * 16 + tt;   // grid = 4096
        const int t = (int)(n & (TT - 1));
        const float xm = (t > 0)      ? x[n - 1] : 0.0f;
        const float x0 = x[n];
        const float xp = (t < TT - 1) ? x[n + 1] : 0.0f;
        res[n * DD + d] = b + w0*xm + w1*x0 + w2*xp;
    }
}

// ---------------------------------------------------------------------------
// c2[s][k] = ||codebook[s][k]||^2 ; one wave per code.
// ---------------------------------------------------------------------------
__global__ __launch_bounds__(256) void c2_kernel(
    const float* __restrict__ cbs, float* __restrict__ c2)
{
    const int w = (int)((blockIdx.x * blockDim.x + threadIdx.x) >> 6);
    const int lane = threadIdx.x & 63;
    if (w >= QS * KC) return;
    const float* row = cbs + (long)w * DD;
    float s = 0.0f;
    #pragma unroll
    for (int q = 0; q < DD / 64; ++q) {
        const float v = row[lane + 64*q];
        s += v * v;
    }
    #pragma unroll
    for (int off = 32; off; off >>= 1) s += __shfl_down(s, off, 64);
    if (lane == 0) c2[w] = s;
}

// ---------------------------------------------------------------------------
// Per-stage codebook f16, pre-swizzled tile-major (R12 layout, proven):
// tile t = cg*4+kp; chunk p = kchunk*64+code at t*4096 + p*8.
// ---------------------------------------------------------------------------
__global__ __launch_bounds__(256) void cb_prep_stage_kernel(
    const float* __restrict__ cb, _Float16* __restrict__ cbh)
{
    const int t = blockIdx.x;          // grid = 64 tiles
    const int cg = t >> 2, kp = t & 3;
    #pragma unroll
    for (int q = 0; q < 2; ++q) {
        const int p = threadIdx.x + 256*q;
        const int code = p & 63, kchunk = p >> 6;
        const float* src = &cb[(long)(cg*64 + code)*DD + kp*64 + kchunk*8];
        const float4 v0 = *reinterpret_cast<const float4*>(src);
        const float4 v1 = *reinterpret_cast<const float4*>(src + 4);
        half8 hv;
        hv[0]=(_Float16)v0.x; hv[1]=(_Float16)v0.y;
        hv[2]=(_Float16)v0.z; hv[3]=(_Float16)v0.w;
        hv[4]=(_Float16)v1.x; hv[5]=(_Float16)v1.y;
        hv[6]=(_Float16)v1.z; hv[7]=(_Float16)v1.w;
        *reinterpret_cast<half8*>(&cbh[(long)t*4096 + p*8]) = hv;
    }
}

// ---------------------------------------------------------------------------
// Fused RVQ stage, f16 MFMA 2-term.
// T4 schedule: 4 LDS buffers, DMA issued 3 rounds ahead, counted
// s_waitcnt vmcnt(4) + RAW s_barrier per round — never drains to 0 in-loop.
// Safety: each wave waits its own round-t DMAs (vmcnt<=4) BEFORE the barrier,
// so after the barrier all waves' chunks of round t are LDS-visible. DMA(t+3)
// (issued after the barrier) targets buf (t-1)&3, which all waves finished
// reading before this barrier.
// ---------------------------------------------------------------------------
__global__ __launch_bounds__(256, 2) void rvq_pass1_kernel(
    const float* __restrict__ cb,      // [KC][DD] fp32 (epilogue gather)
    const _Float16* __restrict__ cbh,  // [64 tiles][4096] f16 swizzled
    const float* __restrict__ c2,      // [KC]
    float* __restrict__ res,           // [NN][DD]
    float* __restrict__ lossAcc,
    int* __restrict__ flagCnt,         // this stage
    int* __restrict__ flagList)        // shared list, cap FLAGCAP
{
    __shared__ __align__(16) _Float16 Bt[4][4096];  // 4 bufs x 8 KB = 32 KB
    __shared__ int idxArr[128];

    const int tid = threadIdx.x;
    const int w   = tid >> 6;
    const int l   = tid & 63;
    const int l15 = l & 15;
    const int l4  = l >> 4;
    const long n0 = (long)blockIdx.x * 128;

    // ---- orientation probe (exact arithmetic; proven rounds 5/10-12) ----
    int tr;
    {
        half8 pa, pb;
        #pragma unroll
        for (int e = 0; e < 8; ++e) {
            pa[e] = (_Float16)l15;
            pb[e] = (_Float16)0.03125f;
        }
        f32x4 pacc = (f32x4){0.f, 0.f, 0.f, 0.f};
        pacc = __builtin_amdgcn_mfma_f32_16x16x32_f16(pa, pb, pacc, 0, 0, 0);
        const float p1 = __shfl(pacc[1], 0, 64);
        tr = (p1 < 0.5f) ? 1 : 0;
    }

    // ---- A fragments: token = n0 + w*32 + mt*16 + l15, k-run (l>>4)*8 ----
    half8 ah[2][8], al[2][8];
    #pragma unroll
    for (int mt = 0; mt < 2; ++mt) {
      #pragma unroll
      for (int kc = 0; kc < 8; ++kc) {
        const long n = n0 + w*32 + mt*16 + l15;
        const float* p = &res[n*DD + kc*32 + l4*8];
        const float4 v0 = *reinterpret_cast<const float4*>(p);
        const float4 v1 = *reinterpret_cast<const float4*>(p + 4);
        const float xv[8] = {v0.x, v0.y, v0.z, v0.w, v1.x, v1.y, v1.z, v1.w};
        half8 hv, lv;
        #pragma unroll
        for (int e = 0; e < 8; ++e) {
            const _Float16 hh = (_Float16)xv[e];
            hv[e] = hh;
            lv[e] = (_Float16)(xv[e] - (float)hh);
        }
        ah[mt][kc] = hv; al[mt][kc] = lv;
      }
    }

    float b1[8], b2[8]; int i1[8];
    #pragma unroll
    for (int r = 0; r < 8; ++r) { b1[r] = 1e30f; b2[r] = 1e30f; i1[r] = 0; }

    // Coalesced DMA: tile t contiguous; thread covers chunks tid, tid+256.
    // 2 gload_lds per wave per round -> vmcnt +2 per staged round.
    auto stageDMA = [&](int t) {
        const _Float16* src = cbh + (long)t*4096;
        const int buf = t & 3;
        gload_lds16(src + ((w*64 + l)*8),        &Bt[buf][w*512]);
        gload_lds16(src + ((256 + w*64 + l)*8),  &Bt[buf][2048 + w*512]);
    };

    // prologue: 3 rounds in flight (6 outstanding DMAs)
    stageDMA(0); stageDMA(1); stageDMA(2);

    for (int cg = 0; cg < 16; ++cg) {
      f32x4 acc[2][4];
      #pragma unroll
      for (int mt = 0; mt < 2; ++mt)
        #pragma unroll
        for (int nt = 0; nt < 4; ++nt)
          acc[mt][nt] = (f32x4){0.f, 0.f, 0.f, 0.f};

      for (int kp = 0; kp < 4; ++kp) {
        const int t = cg*4 + kp, buf = t & 3;

        // counted wait: own round-t DMAs landed (t+1,t+2 may stay in flight)
        if (t < 62)       asm volatile("s_waitcnt vmcnt(4)" ::: "memory");
        else if (t == 62) asm volatile("s_waitcnt vmcnt(2)" ::: "memory");
        else              asm volatile("s_waitcnt vmcnt(0)" ::: "memory");
        __builtin_amdgcn_sched_barrier(0);
        __builtin_amdgcn_s_barrier();      // raw: no vmcnt(0) drain
        __builtin_amdgcn_sched_barrier(0);

        if (t < 61) stageDMA(t + 3);       // into buf (t-1)&3 — reuse-safe

        #pragma unroll
        for (int kc2 = 0; kc2 < 2; ++kc2) {
          const int kc = kp*2 + kc2;
          #pragma unroll
          for (int nt = 0; nt < 4; ++nt) {
            const int slot = ((kc2*4 + l4)*64 + nt*16 + l15)*8;
            const half8 bh = *reinterpret_cast<const half8*>(&Bt[buf][slot]);
            #pragma unroll
            for (int mt = 0; mt < 2; ++mt) {
              acc[mt][nt] = __builtin_amdgcn_mfma_f32_16x16x32_f16(ah[mt][kc], bh, acc[mt][nt], 0, 0, 0);
              acc[mt][nt] = __builtin_amdgcn_mfma_f32_16x16x32_f16(al[mt][kc], bh, acc[mt][nt], 0, 0, 0);
            }
          }
        }
      }

      if (tr == 0) {
        // token on reg side (row=l4*4+j), code on lane side (col=l15)
        #pragma unroll
        for (int nt = 0; nt < 4; ++nt) {
          const int code = cg*64 + nt*16 + l15;
          const float cc = c2[code];
          #pragma unroll
          for (int mt = 0; mt < 2; ++mt) {
            #pragma unroll
            for (int j = 0; j < 4; ++j) {
              const float dist = cc - 2.0f*acc[mt][nt][j];
              const int r = mt*4 + j;
              if (dist < b1[r])      { b2[r] = b1[r]; b1[r] = dist; i1[r] = code; }
              else if (dist < b2[r]) { b2[r] = dist; }
            }
          }
        }
      } else {
        // token on lane side (l15), code on reg side (l4*4+j)
        #pragma unroll
        for (int nt = 0; nt < 4; ++nt) {
          #pragma unroll
          for (int j = 0; j < 4; ++j) {
            const int code = cg*64 + nt*16 + l4*4 + j;
            const float cc = c2[code];
            #pragma unroll
            for (int mt = 0; mt < 2; ++mt) {
              const float dist = cc - 2.0f*acc[mt][nt][j];
              if (dist < b1[mt])      { b2[mt] = b1[mt]; b1[mt] = dist; i1[mt] = code; }
              else if (dist < b2[mt]) { b2[mt] = dist; }
            }
          }
        }
      }
    }

    if (tr == 0) {
      #pragma unroll
      for (int m = 1; m < 16; m <<= 1) {
        #pragma unroll
        for (int r = 0; r < 8; ++r) {
          const float ob1 = __shfl_xor(b1[r], m, 64);
          const float ob2 = __shfl_xor(b2[r], m, 64);
          const int   oi1 = __shfl_xor(i1[r], m, 64);
          const float nb2 = fminf(fminf(b2[r], ob2), fmaxf(b1[r], ob1));
          if (ob1 < b1[r] || (ob1 == b1[r] && oi1 < i1[r])) { b1[r] = ob1; i1[r] = oi1; }
          b2[r] = nb2;
        }
      }
      if (l15 == 0) {
        #pragma unroll
        for (int mt = 0; mt < 2; ++mt)
          #pragma unroll
          for (int j = 0; j < 4; ++j) {
            const int r = mt*4 + j;
            const int row = w*32 + mt*16 + l4*4 + j;
            idxArr[row] = i1[r];
            if (b2[r] - b1[r] < TAU) {
              const int pos = atomicAdd(flagCnt, 1);
              if (pos < FLAGCAP)
                flagList[pos] = (int)(((n0 + row) << 10) | (unsigned)i1[r]);
            }
          }
      }
    } else {
      #pragma unroll
      for (int m = 16; m <= 32; m <<= 1) {
        #pragma unroll
        for (int r = 0; r < 2; ++r) {
          const float ob1 = __shfl_xor(b1[r], m, 64);
          const float ob2 = __shfl_xor(b2[r], m, 64);
          const int   oi1 = __shfl_xor(i1[r], m, 64);
          const float nb2 = fminf(fminf(b2[r], ob2), fmaxf(b1[r], ob1));
          if (ob1 < b1[r] || (ob1 == b1[r] && oi1 < i1[r])) { b1[r] = ob1; i1[r] = oi1; }
          b2[r] = nb2;
        }
      }
      if (l4 == 0) {
        #pragma unroll
        for (int mt = 0; mt < 2; ++mt) {
          const int row = w*32 + mt*16 + l15;
          idxArr[row] = i1[mt];
          if (b2[mt] - b1[mt] < TAU) {
            const int pos = atomicAdd(flagCnt, 1);
            if (pos < FLAGCAP)
              flagList[pos] = (int)(((n0 + row) << 10) | (unsigned)i1[mt]);
          }
        }
      }
    }
    __syncthreads();   // full barrier before idxArr consumption (once)

    // residual update in place + commitment-loss partial (float4 vectorized)
    float lsum = 0.0f;
    const int rw = tid >> 6;        // row-within-quad
    const int cc4 = (tid & 63) * 4; // column base
    #pragma unroll 4
    for (int it = 0; it < 32; ++it) {
        const int r = it*4 + rw;
        const long n = n0 + r;
        const int ix = idxArr[r];
        float4 rv = *reinterpret_cast<const float4*>(&res[n*DD + cc4]);
        const float4 cv = *reinterpret_cast<const float4*>(&cb[(long)ix*DD + cc4]);
        rv.x -= cv.x; rv.y -= cv.y; rv.z -= cv.z; rv.w -= cv.w;
        *reinterpret_cast<float4*>(&res[n*DD + cc4]) = rv;
        lsum += rv.x*rv.x + rv.y*rv.y + rv.z*rv.z + rv.w*rv.w;
    }
    #pragma unroll
    for (int off = 32; off; off >>= 1) lsum += __shfl_down(lsum, off, 64);
    if (l == 0) atomicAdd(lossAcc, lsum);
}

// ---------------------------------------------------------------------------
// Exact fp32 recheck for margin-flagged tokens. Fixed grid, grid-strided.
// ---------------------------------------------------------------------------
__global__ __launch_bounds__(256) void recheck_kernel(
    const float* __restrict__ cb, const float* __restrict__ c2,
    float* __restrict__ res, float* __restrict__ lossAcc,
    const int* __restrict__ flagCnt, const int* __restrict__ flagList)
{
    __shared__ float rorig[DD];
    __shared__ float sD[256];
    __shared__ int   sI[256];
    const int cnt = min(*flagCnt, FLAGCAP);
    const int tid = threadIdx.x;
    for (int f = blockIdx.x; f < cnt; f += gridDim.x) {
        const int packed = flagList[f];
        const long n  = packed >> 10;
        const int old = packed & 1023;
        __syncthreads();   // protect LDS reuse across f-iterations
        const float rme = res[n*DD + tid] + cb[(long)old*DD + tid];
        rorig[tid] = rme;
        __syncthreads();
        float bd = 1e30f; int bi = 0;
        #pragma unroll
        for (int q = 0; q < 4; ++q) {
            const int code = tid + 256*q;
            const float* crow = &cb[(long)code*DD];
            float dot = 0.f;
            for (int d = 0; d < DD; ++d) dot += rorig[d]*crow[d];
            const float dist = c2[code] - 2.0f*dot;
            if (dist < bd || (dist == bd && code < bi)) { bd = dist; bi = code; }
        }
        sD[tid] = bd; sI[tid] = bi;
        __syncthreads();
        for (int s = 128; s; s >>= 1) {
            if (tid < s) {
                const float d2 = sD[tid + s]; const int i2 = sI[tid + s];
                if (d2 < sD[tid] || (d2 == sD[tid] && i2 < sI[tid])) { sD[tid] = d2; sI[tid] = i2; }
            }
            __syncthreads();
        }
        const int best = sI[0];
        if (best != old) {
            const float rn = rorig[tid] - cb[(long)best*DD + tid];
            const float ro = res[n*DD + tid];
            res[n*DD + tid] = rn;
            float delta = rn*rn - ro*ro;
            #pragma unroll
            for (int off = 32; off; off >>= 1) delta += __shfl_down(delta, off, 64);
            if ((tid & 63) == 0) atomicAdd(lossAcc, delta);
        }
    }
}

// ---------------------------------------------------------------------------
// Decoder: quant = z - res_final (z recomputed); conv1d to 1 channel + loss out.
// ---------------------------------------------------------------------------
__global__ __launch_bounds__(256) void decode_kernel(
    const float* __restrict__ x,  const float* __restrict__ ew,
    const float* __restrict__ eb, const float* __restrict__ res,
    const float* __restrict__ dw, const float* __restrict__ db,
    const float* __restrict__ lossAcc, float* __restrict__ out)
{
    const long n = (long)blockIdx.x * 4 + (threadIdx.x >> 6);
    const int lane = threadIdx.x & 63;
    const int t = (int)(n & (TT - 1));
    float sum = 0.0f;
    #pragma unroll
    for (int k = 0; k < 3; ++k) {
        const int tm = t + k - 1;
        if (tm < 0 || tm > TT - 1) continue;
        const long m = n + k - 1;
        const float xm = (tm > 0)      ? x[m - 1] : 0.0f;
        const float x0 = x[m];
        const float xp = (tm < TT - 1) ? x[m + 1] : 0.0f;
        #pragma unroll
        for (int q = 0; q < 4; ++q) {
            const int d = lane + 64 * q;
            const float z = eb[d] + ew[d*3]*xm + ew[d*3 + 1]*x0 + ew[d*3 + 2]*xp;
            const float quant = z - res[m * DD + d];
            sum += quant * dw[d*3 + k];
        }
    }
    #pragma unroll
    for (int off = 32; off; off >>= 1) sum += __shfl_down(sum, off, 64);
    if (lane == 0) out[n] = sum + db[0];
    if (blockIdx.x == 0 && threadIdx.x == 0)
        out[NN] = lossAcc[0] * (1.0f / ((float)NN * (float)DD));
}

// ---------------------------------------------------------------------------
// Workspace: d_ws = res 64MB + lossAcc(16B) + per-stage cbh 512KB (~64.5MB).
// d_out scratch until decode: [0..7]=flagCnt[8], [8..8199]=c2, [8200..]=flagList.
// ---------------------------------------------------------------------------
extern "C" void kernel_launch(void* const* d_in, const int* in_sizes, int n_in,
                              void* d_out, int out_size, void* d_ws, size_t ws_size,
                              hipStream_t stream)
{
    const float* x     = (const float*)d_in[0];
    const float* enc_w = (const float*)d_in[1];
    const float* enc_b = (const float*)d_in[2];
    const float* dec_w = (const float*)d_in[3];
    const float* dec_b = (const float*)d_in[4];
    const float* cbs   = (const float*)d_in[5];
    float* out = (float*)d_out;

    float*    res      = (float*)d_ws;               // [NN][DD] = 64 MB
    float*    lossAcc  = res + (size_t)NN * DD;      // 1 float (+pad)
    _Float16* cbh      = (_Float16*)(lossAcc + 4);   // [64][4096] f16 = 512 KB
    int*      flagCnt  = (int*)out;                  // [QS] in d_out
    float*    c2       = out + 8;                    // [QS*KC] in d_out
    int*      flagList = (int*)(out + 8 + QS * KC);  // cap FLAGCAP in d_out

    hipLaunchKernelGGL(encode_init_kernel, dim3(NN / 16), dim3(256), 0, stream,
                       x, enc_w, enc_b, res, lossAcc, flagCnt);
    hipLaunchKernelGGL(c2_kernel, dim3(QS * KC / 4), dim3(256), 0, stream,
                       cbs, c2);
    for (int s = 0; s < QS; ++s) {
        hipLaunchKernelGGL(cb_prep_stage_kernel, dim3(64), dim3(256), 0, stream,
                           cbs + (size_t)s * KC * DD, cbh);
        hipLaunchKernelGGL(rvq_pass1_kernel, dim3(NN / 128), dim3(256), 0, stream,
                           cbs + (size_t)s * KC * DD, cbh,
                           c2 + (size_t)s * KC,
                           res, lossAcc, flagCnt + s, flagList);
        hipLaunchKernelGGL(recheck_kernel, dim3(256), dim3(256), 0, stream,
                           cbs + (size_t)s * KC * DD,
                           c2 + (size_t)s * KC,
                           res, lossAcc, flagCnt + s, flagList);
    }
    hipLaunchKernelGGL(decode_kernel, dim3(NN / 4), dim3(256), 0, stream,
                       x, enc_w, enc_b, res, dec_w, dec_b, lossAcc, out);
}